// Round 1
// baseline (8849.332 us; speedup 1.0000x reference)
//
#include <hip/hip_runtime.h>

// ---------------- constants ----------------
#define T_LEN 512
#define BATCH 32
#define HDIR  256
#define KTAG  24
#define START_TAG 22
#define STOP_TAG  23
#define NEGV  (-10000.0f)

// workspace layout (float elements)
#define XPROJ_OFF   0ull
#define XPROJ_ELEMS (2ull*512*1024*32)            // [dir][t][row1024][b32]
#define HS_OFF      (XPROJ_OFF + XPROJ_ELEMS)     // [t][b][512]
#define HS_ELEMS    (512ull*32*512)
#define FEATS_OFF   (HS_OFF + HS_ELEMS)           // [t][b][24]
#define FEATS_ELEMS (512ull*32*24)
#define HG_OFF      (FEATS_OFF + FEATS_ELEMS)     // [buf2][dir2][b32][k256]
#define HG_ELEMS    (2ull*2*32*256)
#define FLAGS_OFF_B ((HG_OFF + HG_ELEMS)*4ull)    // bytes; int flags, stride 16 ints per slot
#define FLAGS_INTS  (513ull*64*16)

__device__ __forceinline__ float fsig(float x) {
  return __builtin_amdgcn_rcpf(1.0f + __expf(-x));
}
__device__ __forceinline__ float ftanh(float x) {
  return 2.0f * __builtin_amdgcn_rcpf(1.0f + __expf(-2.0f * x)) - 1.0f;
}

// ---------------- K1: zero flags ----------------
__global__ void k_zero(int* __restrict__ p, int n) {
  int i = blockIdx.x * blockDim.x + threadIdx.x;
  if (i < n) p[i] = 0;
}

// ---------------- K2: embedding gather + input projection GEMM ----------------
// xproj[dir][t][row][b] = emb[sent[b][t]] . w_ih_dir[row] + b_ih[row] + b_hh[row]
__global__ __launch_bounds__(256) void k_xproj(
    const int* __restrict__ sent, const float* __restrict__ emb,
    const float* __restrict__ wf, const float* __restrict__ wb,
    const float* __restrict__ bihf, const float* __restrict__ bhhf,
    const float* __restrict__ bihb, const float* __restrict__ bhhb,
    float* __restrict__ xproj)
{
  __shared__ float As[16][132];   // [k][m], pad 4 -> f4-aligned rows, 2-way banks
  __shared__ float Bs[16][132];   // [k][n]
  __shared__ int sid[128];
  const int tid = threadIdx.x;
  const int m0 = blockIdx.x * 128;
  const int n0 = blockIdx.y * 128;
  const int dir = blockIdx.z;
  const float* __restrict__ W = dir ? wb : wf;
  if (tid < 128) {
    int m = m0 + tid;                       // m = t*32 + b
    sid[tid] = sent[(m & 31) * 512 + (m >> 5)];
  }
  __syncthreads();
  float acc[8][8];
#pragma unroll
  for (int i = 0; i < 8; ++i)
#pragma unroll
    for (int j = 0; j < 8; ++j) acc[i][j] = 0.f;
  const int r = tid >> 1, qq = tid & 1;
  const int ty = tid >> 4, tx = tid & 15;
  for (int k0 = 0; k0 < 256; k0 += 16) {
    const float* ap = &emb[(size_t)sid[r] * 256 + k0 + qq * 8];
    const float* bp = &W[(size_t)(n0 + r) * 256 + k0 + qq * 8];
    float4 a0 = *(const float4*)ap;
    float4 a1 = *(const float4*)(ap + 4);
    float4 b0 = *(const float4*)bp;
    float4 b1 = *(const float4*)(bp + 4);
    __syncthreads();
    As[qq*8+0][r] = a0.x; As[qq*8+1][r] = a0.y; As[qq*8+2][r] = a0.z; As[qq*8+3][r] = a0.w;
    As[qq*8+4][r] = a1.x; As[qq*8+5][r] = a1.y; As[qq*8+6][r] = a1.z; As[qq*8+7][r] = a1.w;
    Bs[qq*8+0][r] = b0.x; Bs[qq*8+1][r] = b0.y; Bs[qq*8+2][r] = b0.z; Bs[qq*8+3][r] = b0.w;
    Bs[qq*8+4][r] = b1.x; Bs[qq*8+5][r] = b1.y; Bs[qq*8+6][r] = b1.z; Bs[qq*8+7][r] = b1.w;
    __syncthreads();
#pragma unroll
    for (int kk = 0; kk < 16; ++kk) {
      float4 av0 = *(const float4*)&As[kk][ty*8];
      float4 av1 = *(const float4*)&As[kk][ty*8+4];
      float4 bv0 = *(const float4*)&Bs[kk][tx*8];
      float4 bv1 = *(const float4*)&Bs[kk][tx*8+4];
      float am[8] = {av0.x,av0.y,av0.z,av0.w,av1.x,av1.y,av1.z,av1.w};
      float bn[8] = {bv0.x,bv0.y,bv0.z,bv0.w,bv1.x,bv1.y,bv1.z,bv1.w};
#pragma unroll
      for (int i = 0; i < 8; ++i)
#pragma unroll
        for (int j = 0; j < 8; ++j)
          acc[i][j] = fmaf(am[i], bn[j], acc[i][j]);
    }
  }
  const float* bi_p = dir ? bihb : bihf;
  const float* bh_p = dir ? bhhb : bhhf;
  float bias[8];
#pragma unroll
  for (int j = 0; j < 8; ++j) { int n = n0 + tx*8 + j; bias[j] = bi_p[n] + bh_p[n]; }
  const int mb = m0 + ty * 8;
  const int tt = mb >> 5, bb = mb & 31;   // 8 consecutive m = same t, consecutive b
#pragma unroll
  for (int j = 0; j < 8; ++j) {
    int n = n0 + tx*8 + j;
    float* dst = &xproj[((((size_t)dir*512 + tt)*1024) + n)*32 + bb];
    float4 s0 = make_float4(acc[0][j]+bias[j], acc[1][j]+bias[j], acc[2][j]+bias[j], acc[3][j]+bias[j]);
    float4 s1 = make_float4(acc[4][j]+bias[j], acc[5][j]+bias[j], acc[6][j]+bias[j], acc[7][j]+bias[j]);
    *(float4*)dst = s0;
    *(float4*)(dst + 4) = s1;
  }
}

// ---------------- K3: persistent bidirectional LSTM ----------------
// 64 WGs: dir = wg>>5, slice = wg&31 (8 h-elems). Per thread:
//   rowg = tid>>5 -> j_local (1 j, all 4 gates); bgrp=(tid>>3)&3 (8 batches); kgrp=tid&7 (32 k's)
// W_hh slice in registers; h staged to LDS (swizzled) each step; 8-way k-split + shfl butterfly.
__global__ __launch_bounds__(256, 1) void k_lstm(
    const float* __restrict__ whhf, const float* __restrict__ whhb,
    const float* __restrict__ h0, const float* __restrict__ c0,
    const float* __restrict__ xproj, float* __restrict__ hglob,
    float* __restrict__ hsout, int* __restrict__ flags)
{
  const int wg = blockIdx.x;           // 0..63
  const int dir = wg >> 5;
  const int slice = wg & 31;
  const int tid = threadIdx.x;
  const int rowg = tid >> 5;           // 0..7 => j_local
  const int bgrp = (tid >> 3) & 3;     // 0..3
  const int kgrp = tid & 7;            // 0..7
  const int jg = slice * 8 + rowg;     // 0..255
  const float* __restrict__ W = dir ? whhb : whhf;
  __shared__ float hl[32 * 256];

  // weights -> registers: w2[gate][kk2] covers k = kgrp*32 + 2*kk2 (+1)
  float2 w2[4][16];
#pragma unroll
  for (int g = 0; g < 4; ++g)
#pragma unroll
    for (int kk2 = 0; kk2 < 16; ++kk2)
      w2[g][kk2] = *(const float2*)&W[(size_t)(g*256 + jg)*256 + kgrp*32 + 2*kk2];

  // cell state (redundant across kgrp lanes)
  float cc[8];
#pragma unroll
  for (int bi = 0; bi < 8; ++bi)
    cc[bi] = c0[(size_t)(dir*32 + bgrp*8 + bi)*256 + jg];

  // init h buffer 0 with our slice of h0
  {
    int b = tid >> 3, jl = tid & 7;
    hglob[((size_t)(0*2 + dir)*32 + b)*256 + slice*8 + jl] =
        h0[(size_t)(dir*32 + b)*256 + slice*8 + jl];
  }
  __syncthreads();
  if (tid == 0)
    __hip_atomic_store(&flags[(0*64 + wg)*16], 1, __ATOMIC_RELEASE, __HIP_MEMORY_SCOPE_AGENT);

  const int rot = (4*kgrp + 2*bgrp) & 31;

  for (int s = 0; s < 512; ++s) {
    const int t = dir ? (511 - s) : s;

    // prefetch additive xproj term early (only kgrp==0 lanes use it)
    float xpr[4][8];
    if (kgrp == 0) {
#pragma unroll
      for (int g = 0; g < 4; ++g) {
        const float* xp = &xproj[((((size_t)dir*512 + t)*1024) + g*256 + jg)*32 + bgrp*8];
        float4 x0 = *(const float4*)xp;
        float4 x1 = *(const float4*)(xp + 4);
        xpr[g][0]=x0.x; xpr[g][1]=x0.y; xpr[g][2]=x0.z; xpr[g][3]=x0.w;
        xpr[g][4]=x1.x; xpr[g][5]=x1.y; xpr[g][6]=x1.z; xpr[g][7]=x1.w;
      }
    }

    // wait for all producers of h(s) in our direction
    if (tid < 32) {
      const int widx = dir*32 + tid;
      while (__hip_atomic_load(&flags[((size_t)s*64 + widx)*16],
                               __ATOMIC_ACQUIRE, __HIP_MEMORY_SCOPE_AGENT) == 0)
        __builtin_amdgcn_s_sleep(1);
    }
    __syncthreads();

    // stage h(s) -> LDS with rotation swizzle (coherent sc1 loads, L1-bypassing)
    {
      const float* hg = hglob + ((size_t)((s & 1)*2 + dir)*32)*256;
      const int kk = tid & 31;
      const int kw4 = 4*((tid >> 5) & 7);
#pragma unroll 4
      for (int it = 0; it < 32; ++it) {
        float v = __hip_atomic_load(&hg[it*256 + tid], __ATOMIC_RELAXED, __HIP_MEMORY_SCOPE_AGENT);
        int rw = (kw4 + 2*((it >> 3) & 3)) & 31;
        hl[it*256 + (tid & ~31) + ((kk + rw) & 31)] = v;
      }
    }
    __syncthreads();

    // gates partial sums over our 32-k slice
    float acc[4][8];
#pragma unroll
    for (int g = 0; g < 4; ++g)
#pragma unroll
      for (int bi = 0; bi < 8; ++bi) acc[g][bi] = 0.f;

    const int hbase = kgrp * 32;
#pragma unroll
    for (int kk2 = 0; kk2 < 16; ++kk2) {
      const int idx = hbase + ((2*kk2 + rot) & 31);
      float2 h2[8];
#pragma unroll
      for (int bi = 0; bi < 8; ++bi)
        h2[bi] = *(const float2*)&hl[(bgrp*8 + bi)*256 + idx];
#pragma unroll
      for (int g = 0; g < 4; ++g)
#pragma unroll
        for (int bi = 0; bi < 8; ++bi) {
          acc[g][bi] = fmaf(w2[g][kk2].x, h2[bi].x, acc[g][bi]);
          acc[g][bi] = fmaf(w2[g][kk2].y, h2[bi].y, acc[g][bi]);
        }
    }

    // add xproj term once (kgrp==0), then butterfly-reduce over the 8 kgrp lanes
    if (kgrp == 0) {
#pragma unroll
      for (int g = 0; g < 4; ++g)
#pragma unroll
        for (int bi = 0; bi < 8; ++bi) acc[g][bi] += xpr[g][bi];
    }
#pragma unroll
    for (int g = 0; g < 4; ++g)
#pragma unroll
      for (int bi = 0; bi < 8; ++bi) {
        float v = acc[g][bi];
        v += __shfl_xor(v, 1, 64);
        v += __shfl_xor(v, 2, 64);
        v += __shfl_xor(v, 4, 64);
        acc[g][bi] = v;
      }

    // LSTM cell update (PyTorch gate order i,f,g,o)
    float hnew[8];
#pragma unroll
    for (int bi = 0; bi < 8; ++bi) {
      float ig = fsig(acc[0][bi]);
      float fg = fsig(acc[1][bi]);
      float gg = ftanh(acc[2][bi]);
      float og = fsig(acc[3][bi]);
      cc[bi] = fg * cc[bi] + ig * gg;
      hnew[bi] = og * ftanh(cc[bi]);
    }
    if (kgrp == 0) {
      float* hgn = hglob + ((size_t)(((s + 1) & 1)*2 + dir)*32)*256;
#pragma unroll
      for (int bi = 0; bi < 8; ++bi) {
        int b = bgrp*8 + bi;
        hgn[b*256 + jg] = hnew[bi];
        hsout[((size_t)t*32 + b)*512 + dir*256 + jg] = hnew[bi];
      }
    }
    __syncthreads();   // drains vmcnt: all stores complete before the release below
    if (tid == 0)
      __hip_atomic_store(&flags[((size_t)(s + 1)*64 + wg)*16], 1,
                         __ATOMIC_RELEASE, __HIP_MEMORY_SCOPE_AGENT);
  }
}

// ---------------- K4: feats = hs @ w_out^T + b_out ----------------
__global__ __launch_bounds__(256) void k_feats(
    const float* __restrict__ hs, const float* __restrict__ wout,
    const float* __restrict__ bout, float* __restrict__ feats)
{
  const int t = blockIdx.x;
  const int tid = threadIdx.x;
  __shared__ float hlds[32 * 516];
  const float* src = hs + (size_t)t * 32 * 512;
#pragma unroll
  for (int it = 0; it < 16; ++it) {
    int f = it * 1024 + tid * 4;
    float4 v = *(const float4*)&src[f];
    int b = f >> 9, k = f & 511;
    *(float4*)&hlds[b * 516 + k] = v;
  }
  __syncthreads();
  const int b = tid >> 3, ks = tid & 7;
#pragma unroll
  for (int kt = 0; kt < 3; ++kt) {
    int k = kt * 8 + ks;
    float acc = bout[k];
    const float* wr = wout + (size_t)k * 512;
#pragma unroll 8
    for (int kk = 0; kk < 512; kk += 4) {
      float4 h4 = *(const float4*)&hlds[b * 516 + kk];
      float4 w4 = *(const float4*)&wr[kk];
      acc += h4.x*w4.x + h4.y*w4.y + h4.z*w4.z + h4.w*w4.w;
    }
    feats[((size_t)t * 32 + b) * 24 + k] = acc;
  }
}

// ---------------- K5: Viterbi + backtrace, one wave per batch element ----------------
__global__ __launch_bounds__(64) void k_viterbi(
    const float* __restrict__ feats, const float* __restrict__ trans,
    float* __restrict__ out)
{
  const int b = blockIdx.x;      // 0..31
  const int lane = threadIdx.x;  // 0..63 ; active tag lane if <24
  const int k = lane;
  __shared__ float fvl[2][32];
  __shared__ float pathb[512];
  __shared__ unsigned char bcol[512 * 24];
  float trr[24];
  if (k < 24) {
#pragma unroll
    for (int pv = 0; pv < 24; ++pv) trr[pv] = trans[k * 24 + pv];
  }
  if (k < 32) fvl[0][k] = (k == START_TAG) ? 0.f : NEGV;
  if (k < 32) fvl[1][k] = NEGV;
  __syncthreads();
  float fcur = (k < 24) ? feats[b * 24 + k] : 0.f;
  int q = 0;
  for (int t = 0; t < 512; ++t) {
    float fnext = (t < 511 && k < 24) ? feats[(size_t)(t + 1) * 768 + b * 24 + k] : 0.f;
    float fvp[24];
    {
      const float4* fp4 = (const float4*)&fvl[q][0];
#pragma unroll
      for (int i = 0; i < 6; ++i) {
        float4 v = fp4[i];
        fvp[i*4+0] = v.x; fvp[i*4+1] = v.y; fvp[i*4+2] = v.z; fvp[i*4+3] = v.w;
      }
    }
    float best = -3.4e38f; int bp = 0;
#pragma unroll
    for (int pv = 0; pv < 24; ++pv) {
      float v = fvp[pv] + trr[pv];
      if (v > best) { best = v; bp = pv; }   // strict > : first-max, matches argmax
    }
    if (k < 24) {
      fvl[q ^ 1][k] = best + fcur;
      bcol[t * 24 + k] = (unsigned char)bp;
    }
    fcur = fnext;
    q ^= 1;
    __syncthreads();
  }
  if (lane == 0) {
    float best = -3.4e38f; int bt = 0;
#pragma unroll
    for (int kk = 0; kk < 24; ++kk) {
      float v = fvl[q][kk] + trans[STOP_TAG * 24 + kk];
      if (v > best) { best = v; bt = kk; }
    }
    out[b] = best;
    pathb[511] = (float)bt;
    int tag = bt;
    for (int t = 511; t >= 1; --t) {
      tag = bcol[t * 24 + tag];       // bps[t] maps tag@t -> tag@t-1
      pathb[t - 1] = (float)tag;
    }
  }
  __syncthreads();
#pragma unroll
  for (int it = 0; it < 8; ++it)
    out[32 + (size_t)b * 512 + it * 64 + lane] = pathb[it * 64 + lane];
}

// ---------------- launch ----------------
extern "C" void kernel_launch(void* const* d_in, const int* in_sizes, int n_in,
                              void* d_out, int out_size, void* d_ws, size_t ws_size,
                              hipStream_t stream) {
  (void)in_sizes; (void)n_in; (void)out_size; (void)ws_size;
  const int*   sent = (const int*)d_in[0];
  const float* emb  = (const float*)d_in[1];
  const float* wihf = (const float*)d_in[2];
  const float* whhf = (const float*)d_in[3];
  const float* bihf = (const float*)d_in[4];
  const float* bhhf = (const float*)d_in[5];
  const float* wihb = (const float*)d_in[6];
  const float* whhb = (const float*)d_in[7];
  const float* bihb = (const float*)d_in[8];
  const float* bhhb = (const float*)d_in[9];
  const float* wout = (const float*)d_in[10];
  const float* bout = (const float*)d_in[11];
  const float* trans= (const float*)d_in[12];
  const float* h0   = (const float*)d_in[13];
  const float* c0   = (const float*)d_in[14];

  float* ws     = (float*)d_ws;
  float* xproj  = ws + XPROJ_OFF;
  float* hs     = ws + HS_OFF;
  float* feats  = ws + FEATS_OFF;
  float* hglob  = ws + HG_OFF;
  int*   flags  = (int*)((unsigned char*)d_ws + FLAGS_OFF_B);

  k_zero<<<(int)((FLAGS_INTS + 255) / 256), 256, 0, stream>>>(flags, (int)FLAGS_INTS);
  k_xproj<<<dim3(128, 8, 2), 256, 0, stream>>>(sent, emb, wihf, wihb,
                                               bihf, bhhf, bihb, bhhb, xproj);
  k_lstm<<<64, 256, 0, stream>>>(whhf, whhb, h0, c0, xproj, hglob, hs, flags);
  k_feats<<<512, 256, 0, stream>>>(hs, wout, bout, feats);
  k_viterbi<<<32, 64, 0, stream>>>(feats, trans, (float*)d_out);
}

// Round 2
// 7620.017 us; speedup vs baseline: 1.1613x; 1.1613x over previous
//
#include <hip/hip_runtime.h>

// ---------------- constants ----------------
#define T_LEN 512
#define BATCH 32
#define HDIR  256
#define KTAG  24
#define START_TAG 22
#define STOP_TAG  23
#define NEGV  (-10000.0f)

// workspace layout (float elements)
#define XPROJ_OFF   0ull
#define XPROJ_ELEMS (2ull*512*1024*32)            // [dir][t][row1024][b32]
#define HS_OFF      (XPROJ_OFF + XPROJ_ELEMS)     // [t][b][512]
#define HS_ELEMS    (512ull*32*512)
#define FEATS_OFF   (HS_OFF + HS_ELEMS)           // [t][b][24]
#define FEATS_ELEMS (512ull*32*24)
#define HG_OFF      (FEATS_OFF + FEATS_ELEMS)     // [buf2][dir2][b32][k256]
#define HG_ELEMS    (2ull*2*32*256)
#define FLAGS_OFF_B ((HG_OFF + HG_ELEMS)*4ull)    // bytes; int flags, stride 16 ints per slot
#define FLAGS_INTS  (513ull*64*16)

__device__ __forceinline__ float fsig(float x) {
  return __builtin_amdgcn_rcpf(1.0f + __expf(-x));
}
__device__ __forceinline__ float ftanh(float x) {
  return 2.0f * __builtin_amdgcn_rcpf(1.0f + __expf(-2.0f * x)) - 1.0f;
}

// ---------------- K1: zero flags ----------------
__global__ void k_zero(int* __restrict__ p, int n) {
  int i = blockIdx.x * blockDim.x + threadIdx.x;
  if (i < n) p[i] = 0;
}

// ---------------- K2: embedding gather + input projection GEMM ----------------
// xproj[dir][t][row][b] = emb[sent[b][t]] . w_ih_dir[row] + b_ih[row] + b_hh[row]
__global__ __launch_bounds__(256) void k_xproj(
    const int* __restrict__ sent, const float* __restrict__ emb,
    const float* __restrict__ wf, const float* __restrict__ wb,
    const float* __restrict__ bihf, const float* __restrict__ bhhf,
    const float* __restrict__ bihb, const float* __restrict__ bhhb,
    float* __restrict__ xproj)
{
  __shared__ float As[16][132];   // [k][m], pad 4 -> f4-aligned rows, 2-way banks
  __shared__ float Bs[16][132];   // [k][n]
  __shared__ int sid[128];
  const int tid = threadIdx.x;
  const int m0 = blockIdx.x * 128;
  const int n0 = blockIdx.y * 128;
  const int dir = blockIdx.z;
  const float* __restrict__ W = dir ? wb : wf;
  if (tid < 128) {
    int m = m0 + tid;                       // m = t*32 + b
    sid[tid] = sent[(m & 31) * 512 + (m >> 5)];
  }
  __syncthreads();
  float acc[8][8];
#pragma unroll
  for (int i = 0; i < 8; ++i)
#pragma unroll
    for (int j = 0; j < 8; ++j) acc[i][j] = 0.f;
  const int r = tid >> 1, qq = tid & 1;
  const int ty = tid >> 4, tx = tid & 15;
  for (int k0 = 0; k0 < 256; k0 += 16) {
    const float* ap = &emb[(size_t)sid[r] * 256 + k0 + qq * 8];
    const float* bp = &W[(size_t)(n0 + r) * 256 + k0 + qq * 8];
    float4 a0 = *(const float4*)ap;
    float4 a1 = *(const float4*)(ap + 4);
    float4 b0 = *(const float4*)bp;
    float4 b1 = *(const float4*)(bp + 4);
    __syncthreads();
    As[qq*8+0][r] = a0.x; As[qq*8+1][r] = a0.y; As[qq*8+2][r] = a0.z; As[qq*8+3][r] = a0.w;
    As[qq*8+4][r] = a1.x; As[qq*8+5][r] = a1.y; As[qq*8+6][r] = a1.z; As[qq*8+7][r] = a1.w;
    Bs[qq*8+0][r] = b0.x; Bs[qq*8+1][r] = b0.y; Bs[qq*8+2][r] = b0.z; Bs[qq*8+3][r] = b0.w;
    Bs[qq*8+4][r] = b1.x; Bs[qq*8+5][r] = b1.y; Bs[qq*8+6][r] = b1.z; Bs[qq*8+7][r] = b1.w;
    __syncthreads();
#pragma unroll
    for (int kk = 0; kk < 16; ++kk) {
      float4 av0 = *(const float4*)&As[kk][ty*8];
      float4 av1 = *(const float4*)&As[kk][ty*8+4];
      float4 bv0 = *(const float4*)&Bs[kk][tx*8];
      float4 bv1 = *(const float4*)&Bs[kk][tx*8+4];
      float am[8] = {av0.x,av0.y,av0.z,av0.w,av1.x,av1.y,av1.z,av1.w};
      float bn[8] = {bv0.x,bv0.y,bv0.z,bv0.w,bv1.x,bv1.y,bv1.z,bv1.w};
#pragma unroll
      for (int i = 0; i < 8; ++i)
#pragma unroll
        for (int j = 0; j < 8; ++j)
          acc[i][j] = fmaf(am[i], bn[j], acc[i][j]);
    }
  }
  const float* bi_p = dir ? bihb : bihf;
  const float* bh_p = dir ? bhhb : bhhf;
  float bias[8];
#pragma unroll
  for (int j = 0; j < 8; ++j) { int n = n0 + tx*8 + j; bias[j] = bi_p[n] + bh_p[n]; }
  const int mb = m0 + ty * 8;
  const int tt = mb >> 5, bb = mb & 31;   // 8 consecutive m = same t, consecutive b
#pragma unroll
  for (int j = 0; j < 8; ++j) {
    int n = n0 + tx*8 + j;
    float* dst = &xproj[((((size_t)dir*512 + tt)*1024) + n)*32 + bb];
    float4 s0 = make_float4(acc[0][j]+bias[j], acc[1][j]+bias[j], acc[2][j]+bias[j], acc[3][j]+bias[j]);
    float4 s1 = make_float4(acc[4][j]+bias[j], acc[5][j]+bias[j], acc[6][j]+bias[j], acc[7][j]+bias[j]);
    *(float4*)dst = s0;
    *(float4*)(dst + 4) = s1;
  }
}

// ---------------- K3: persistent bidirectional LSTM ----------------
// 64 WGs: dir = wg>>5, slice = wg&31 (8 h-elems). Per thread:
//   rowg = tid>>5 -> j_local (1 j, all 4 gates); bgrp=(tid>>3)&3 (8 batches); kgrp=tid&7 (32 k's)
// W_hh slice in registers; h staged to LDS (swizzled) each step; 8-way k-split + shfl butterfly.
// Sync design (round 2): ALL cross-WG data moves via RELAXED agent-scope atomics
// (sc0/sc1 -> L3 coherence point). No acquire/release => no buffer_inv / buffer_wbl2
// per step. Ordering: h stores -> __syncthreads (drains vmcnt before s_barrier) ->
// relaxed flag store; consumer: relaxed poll -> signal_fence -> staging loads
// (in-order VMEM issue per wave).
__global__ __launch_bounds__(256, 1) void k_lstm(
    const float* __restrict__ whhf, const float* __restrict__ whhb,
    const float* __restrict__ h0, const float* __restrict__ c0,
    const float* __restrict__ xproj, float* __restrict__ hglob,
    float* __restrict__ hsout, int* __restrict__ flags)
{
  const int wg = blockIdx.x;           // 0..63
  const int dir = wg >> 5;
  const int slice = wg & 31;
  const int tid = threadIdx.x;
  const int rowg = tid >> 5;           // 0..7 => j_local
  const int bgrp = (tid >> 3) & 3;     // 0..3
  const int kgrp = tid & 7;            // 0..7
  const int jg = slice * 8 + rowg;     // 0..255
  const float* __restrict__ W = dir ? whhb : whhf;
  __shared__ float hl[32 * 256];

  // weights -> registers: w2[gate][kk2] covers k = kgrp*32 + 2*kk2 (+1)
  float2 w2[4][16];
#pragma unroll
  for (int g = 0; g < 4; ++g)
#pragma unroll
    for (int kk2 = 0; kk2 < 16; ++kk2)
      w2[g][kk2] = *(const float2*)&W[(size_t)(g*256 + jg)*256 + kgrp*32 + 2*kk2];

  // cell state (redundant across kgrp lanes)
  float cc[8];
#pragma unroll
  for (int bi = 0; bi < 8; ++bi)
    cc[bi] = c0[(size_t)(dir*32 + bgrp*8 + bi)*256 + jg];

  // init h buffer 0 with our slice of h0 (write-through to L3)
  {
    int b = tid >> 3, jl = tid & 7;
    __hip_atomic_store(
        &hglob[((size_t)(0*2 + dir)*32 + b)*256 + slice*8 + jl],
        h0[(size_t)(dir*32 + b)*256 + slice*8 + jl],
        __ATOMIC_RELAXED, __HIP_MEMORY_SCOPE_AGENT);
  }
  __syncthreads();   // drains vmcnt -> h0 slice is at L3 before flag
  if (tid == 0)
    __hip_atomic_store(&flags[(0*64 + wg)*16], 1, __ATOMIC_RELAXED, __HIP_MEMORY_SCOPE_AGENT);

  const int rot = (4*kgrp + 2*bgrp) & 31;
  // producer WG of this thread's staging column j = tid
  const int prodw = dir*32 + (tid >> 3);

  for (int s = 0; s < 512; ++s) {
    const int t = dir ? (511 - s) : s;

    // prefetch additive xproj term early (only kgrp==0 lanes use it)
    float xpr[4][8];
    if (kgrp == 0) {
#pragma unroll
      for (int g = 0; g < 4; ++g) {
        const float* xp = &xproj[((((size_t)dir*512 + t)*1024) + g*256 + jg)*32 + bgrp*8];
        float4 x0 = *(const float4*)xp;
        float4 x1 = *(const float4*)(xp + 4);
        xpr[g][0]=x0.x; xpr[g][1]=x0.y; xpr[g][2]=x0.z; xpr[g][3]=x0.w;
        xpr[g][4]=x1.x; xpr[g][5]=x1.y; xpr[g][6]=x1.z; xpr[g][7]=x1.w;
      }
    }

    // wait only for the producer of OUR staging column, then stage it
    // (pipelines staging of early producers while late ones finish)
    while (__hip_atomic_load(&flags[((size_t)s*64 + prodw)*16],
                             __ATOMIC_RELAXED, __HIP_MEMORY_SCOPE_AGENT) == 0)
      __builtin_amdgcn_s_sleep(1);
    __atomic_signal_fence(__ATOMIC_ACQ_REL);  // compiler-only: keep loads below poll

    // stage h(s) column j=tid -> LDS with rotation swizzle
    {
      const float* hg = hglob + ((size_t)((s & 1)*2 + dir)*32)*256;
      const int kk = tid & 31;
      const int kw4 = 4*((tid >> 5) & 7);
#pragma unroll 4
      for (int it = 0; it < 32; ++it) {
        float v = __hip_atomic_load(&hg[it*256 + tid], __ATOMIC_RELAXED, __HIP_MEMORY_SCOPE_AGENT);
        int rw = (kw4 + 2*((it >> 3) & 3)) & 31;
        hl[it*256 + (tid & ~31) + ((kk + rw) & 31)] = v;
      }
    }
    __syncthreads();

    // gates partial sums over our 32-k slice
    float acc[4][8];
#pragma unroll
    for (int g = 0; g < 4; ++g)
#pragma unroll
      for (int bi = 0; bi < 8; ++bi) acc[g][bi] = 0.f;

    const int hbase = kgrp * 32;
#pragma unroll
    for (int kk2 = 0; kk2 < 16; ++kk2) {
      const int idx = hbase + ((2*kk2 + rot) & 31);
      float2 h2[8];
#pragma unroll
      for (int bi = 0; bi < 8; ++bi)
        h2[bi] = *(const float2*)&hl[(bgrp*8 + bi)*256 + idx];
#pragma unroll
      for (int g = 0; g < 4; ++g)
#pragma unroll
        for (int bi = 0; bi < 8; ++bi) {
          acc[g][bi] = fmaf(w2[g][kk2].x, h2[bi].x, acc[g][bi]);
          acc[g][bi] = fmaf(w2[g][kk2].y, h2[bi].y, acc[g][bi]);
        }
    }

    // add xproj term once (kgrp==0), then butterfly-reduce over the 8 kgrp lanes
    if (kgrp == 0) {
#pragma unroll
      for (int g = 0; g < 4; ++g)
#pragma unroll
        for (int bi = 0; bi < 8; ++bi) acc[g][bi] += xpr[g][bi];
    }
#pragma unroll
    for (int g = 0; g < 4; ++g)
#pragma unroll
      for (int bi = 0; bi < 8; ++bi) {
        float v = acc[g][bi];
        v += __shfl_xor(v, 1, 64);
        v += __shfl_xor(v, 2, 64);
        v += __shfl_xor(v, 4, 64);
        acc[g][bi] = v;
      }

    // LSTM cell update (PyTorch gate order i,f,g,o)
    float hnew[8];
#pragma unroll
    for (int bi = 0; bi < 8; ++bi) {
      float ig = fsig(acc[0][bi]);
      float fg = fsig(acc[1][bi]);
      float gg = ftanh(acc[2][bi]);
      float og = fsig(acc[3][bi]);
      cc[bi] = fg * cc[bi] + ig * gg;
      hnew[bi] = og * ftanh(cc[bi]);
    }
    if (kgrp == 0) {
      float* hgn = hglob + ((size_t)(((s + 1) & 1)*2 + dir)*32)*256;
#pragma unroll
      for (int bi = 0; bi < 8; ++bi) {
        int b = bgrp*8 + bi;
        __hip_atomic_store(&hgn[b*256 + jg], hnew[bi],
                           __ATOMIC_RELAXED, __HIP_MEMORY_SCOPE_AGENT);
        hsout[((size_t)t*32 + b)*512 + dir*256 + jg] = hnew[bi];
      }
    }
    __syncthreads();   // drains vmcnt: all h stores at L3 before the flag below
    if (tid == 0)
      __hip_atomic_store(&flags[((size_t)(s + 1)*64 + wg)*16], 1,
                         __ATOMIC_RELAXED, __HIP_MEMORY_SCOPE_AGENT);
  }
}

// ---------------- K4: feats = hs @ w_out^T + b_out ----------------
__global__ __launch_bounds__(256) void k_feats(
    const float* __restrict__ hs, const float* __restrict__ wout,
    const float* __restrict__ bout, float* __restrict__ feats)
{
  const int t = blockIdx.x;
  const int tid = threadIdx.x;
  __shared__ float hlds[32 * 516];
  const float* src = hs + (size_t)t * 32 * 512;
#pragma unroll
  for (int it = 0; it < 16; ++it) {
    int f = it * 1024 + tid * 4;
    float4 v = *(const float4*)&src[f];
    int b = f >> 9, k = f & 511;
    *(float4*)&hlds[b * 516 + k] = v;
  }
  __syncthreads();
  const int b = tid >> 3, ks = tid & 7;
#pragma unroll
  for (int kt = 0; kt < 3; ++kt) {
    int k = kt * 8 + ks;
    float acc = bout[k];
    const float* wr = wout + (size_t)k * 512;
#pragma unroll 8
    for (int kk = 0; kk < 512; kk += 4) {
      float4 h4 = *(const float4*)&hlds[b * 516 + kk];
      float4 w4 = *(const float4*)&wr[kk];
      acc += h4.x*w4.x + h4.y*w4.y + h4.z*w4.z + h4.w*w4.w;
    }
    feats[((size_t)t * 32 + b) * 24 + k] = acc;
  }
}

// ---------------- K5: Viterbi + backtrace, one wave per batch element ----------------
__global__ __launch_bounds__(64) void k_viterbi(
    const float* __restrict__ feats, const float* __restrict__ trans,
    float* __restrict__ out)
{
  const int b = blockIdx.x;      // 0..31
  const int lane = threadIdx.x;  // 0..63 ; active tag lane if <24
  const int k = lane;
  __shared__ float fvl[2][32];
  __shared__ float pathb[512];
  __shared__ unsigned char bcol[512 * 24];
  float trr[24];
  if (k < 24) {
#pragma unroll
    for (int pv = 0; pv < 24; ++pv) trr[pv] = trans[k * 24 + pv];
  }
  if (k < 32) fvl[0][k] = (k == START_TAG) ? 0.f : NEGV;
  if (k < 32) fvl[1][k] = NEGV;
  __syncthreads();
  float fcur = (k < 24) ? feats[b * 24 + k] : 0.f;
  int q = 0;
  for (int t = 0; t < 512; ++t) {
    float fnext = (t < 511 && k < 24) ? feats[(size_t)(t + 1) * 768 + b * 24 + k] : 0.f;
    float fvp[24];
    {
      const float4* fp4 = (const float4*)&fvl[q][0];
#pragma unroll
      for (int i = 0; i < 6; ++i) {
        float4 v = fp4[i];
        fvp[i*4+0] = v.x; fvp[i*4+1] = v.y; fvp[i*4+2] = v.z; fvp[i*4+3] = v.w;
      }
    }
    float best = -3.4e38f; int bp = 0;
#pragma unroll
    for (int pv = 0; pv < 24; ++pv) {
      float v = fvp[pv] + trr[pv];
      if (v > best) { best = v; bp = pv; }   // strict > : first-max, matches argmax
    }
    if (k < 24) {
      fvl[q ^ 1][k] = best + fcur;
      bcol[t * 24 + k] = (unsigned char)bp;
    }
    fcur = fnext;
    q ^= 1;
    __syncthreads();
  }
  if (lane == 0) {
    float best = -3.4e38f; int bt = 0;
#pragma unroll
    for (int kk = 0; kk < 24; ++kk) {
      float v = fvl[q][kk] + trans[STOP_TAG * 24 + kk];
      if (v > best) { best = v; bt = kk; }
    }
    out[b] = best;
    pathb[511] = (float)bt;
    int tag = bt;
    for (int t = 511; t >= 1; --t) {
      tag = bcol[t * 24 + tag];       // bps[t] maps tag@t -> tag@t-1
      pathb[t - 1] = (float)tag;
    }
  }
  __syncthreads();
#pragma unroll
  for (int it = 0; it < 8; ++it)
    out[32 + (size_t)b * 512 + it * 64 + lane] = pathb[it * 64 + lane];
}

// ---------------- launch ----------------
extern "C" void kernel_launch(void* const* d_in, const int* in_sizes, int n_in,
                              void* d_out, int out_size, void* d_ws, size_t ws_size,
                              hipStream_t stream) {
  (void)in_sizes; (void)n_in; (void)out_size; (void)ws_size;
  const int*   sent = (const int*)d_in[0];
  const float* emb  = (const float*)d_in[1];
  const float* wihf = (const float*)d_in[2];
  const float* whhf = (const float*)d_in[3];
  const float* bihf = (const float*)d_in[4];
  const float* bhhf = (const float*)d_in[5];
  const float* wihb = (const float*)d_in[6];
  const float* whhb = (const float*)d_in[7];
  const float* bihb = (const float*)d_in[8];
  const float* bhhb = (const float*)d_in[9];
  const float* wout = (const float*)d_in[10];
  const float* bout = (const float*)d_in[11];
  const float* trans= (const float*)d_in[12];
  const float* h0   = (const float*)d_in[13];
  const float* c0   = (const float*)d_in[14];

  float* ws     = (float*)d_ws;
  float* xproj  = ws + XPROJ_OFF;
  float* hs     = ws + HS_OFF;
  float* feats  = ws + FEATS_OFF;
  float* hglob  = ws + HG_OFF;
  int*   flags  = (int*)((unsigned char*)d_ws + FLAGS_OFF_B);

  k_zero<<<(int)((FLAGS_INTS + 255) / 256), 256, 0, stream>>>(flags, (int)FLAGS_INTS);
  k_xproj<<<dim3(128, 8, 2), 256, 0, stream>>>(sent, emb, wihf, wihb,
                                               bihf, bhhf, bihb, bhhb, xproj);
  k_lstm<<<64, 256, 0, stream>>>(whhf, whhb, h0, c0, xproj, hglob, hs, flags);
  k_feats<<<512, 256, 0, stream>>>(hs, wout, bout, feats);
  k_viterbi<<<32, 64, 0, stream>>>(feats, trans, (float*)d_out);
}

// Round 3
// 4946.206 us; speedup vs baseline: 1.7891x; 1.5406x over previous
//
#include <hip/hip_runtime.h>

// ---------------- constants ----------------
#define T_LEN 512
#define BATCH 32
#define HDIR  256
#define KTAG  24
#define START_TAG 22
#define STOP_TAG  23
#define NEGV  (-10000.0f)
#define SENTU 0x7FC0DEADu   // NaN payload; h = sig*tanh can never be NaN

typedef float vf4 __attribute__((ext_vector_type(4)));

// workspace layout (float elements)
#define XPROJ_OFF   0ull
#define XPROJ_ELEMS (2ull*512*1024*32)            // [dir][t][row1024][b32]
#define FEATS_OFF   (XPROJ_OFF + XPROJ_ELEMS)     // [t][b][24]
#define FEATS_ELEMS (512ull*32*24)
#define HIST_OFF    (FEATS_OFF + FEATS_ELEMS)     // [dir][slot513][bh8][j256][bl4]
#define HIST_ELEMS  (2ull*513*8192)

__device__ __forceinline__ float fsig(float x) {
  return __builtin_amdgcn_rcpf(1.0f + __expf(-x));
}
__device__ __forceinline__ float ftanh(float x) {
  return 2.0f * __builtin_amdgcn_rcpf(1.0f + __expf(-2.0f * x)) - 1.0f;
}
__device__ __forceinline__ unsigned um(unsigned a, unsigned b) { return a < b ? a : b; }

// ---------------- K1: sentinel-fill hist ----------------
__global__ void k_fill(unsigned* __restrict__ p, int n) {
  int i = blockIdx.x * blockDim.x + threadIdx.x;
  if (i < n)
    __hip_atomic_store(&p[i], SENTU, __ATOMIC_RELAXED, __HIP_MEMORY_SCOPE_AGENT);
}

// ---------------- K2: embedding gather + input projection GEMM ----------------
// xproj[dir][t][row][b] = emb[sent[b][t]] . w_ih_dir[row] + b_ih[row] + b_hh[row]
__global__ __launch_bounds__(256) void k_xproj(
    const int* __restrict__ sent, const float* __restrict__ emb,
    const float* __restrict__ wf, const float* __restrict__ wb,
    const float* __restrict__ bihf, const float* __restrict__ bhhf,
    const float* __restrict__ bihb, const float* __restrict__ bhhb,
    float* __restrict__ xproj)
{
  __shared__ float As[16][132];   // [k][m]
  __shared__ float Bs[16][132];   // [k][n]
  __shared__ int sid[128];
  const int tid = threadIdx.x;
  const int m0 = blockIdx.x * 128;
  const int n0 = blockIdx.y * 128;
  const int dir = blockIdx.z;
  const float* __restrict__ W = dir ? wb : wf;
  if (tid < 128) {
    int m = m0 + tid;                       // m = t*32 + b
    sid[tid] = sent[(m & 31) * 512 + (m >> 5)];
  }
  __syncthreads();
  float acc[8][8];
#pragma unroll
  for (int i = 0; i < 8; ++i)
#pragma unroll
    for (int j = 0; j < 8; ++j) acc[i][j] = 0.f;
  const int r = tid >> 1, qq = tid & 1;
  const int ty = tid >> 4, tx = tid & 15;
  for (int k0 = 0; k0 < 256; k0 += 16) {
    const float* ap = &emb[(size_t)sid[r] * 256 + k0 + qq * 8];
    const float* bp = &W[(size_t)(n0 + r) * 256 + k0 + qq * 8];
    float4 a0 = *(const float4*)ap;
    float4 a1 = *(const float4*)(ap + 4);
    float4 b0 = *(const float4*)bp;
    float4 b1 = *(const float4*)(bp + 4);
    __syncthreads();
    As[qq*8+0][r] = a0.x; As[qq*8+1][r] = a0.y; As[qq*8+2][r] = a0.z; As[qq*8+3][r] = a0.w;
    As[qq*8+4][r] = a1.x; As[qq*8+5][r] = a1.y; As[qq*8+6][r] = a1.z; As[qq*8+7][r] = a1.w;
    Bs[qq*8+0][r] = b0.x; Bs[qq*8+1][r] = b0.y; Bs[qq*8+2][r] = b0.z; Bs[qq*8+3][r] = b0.w;
    Bs[qq*8+4][r] = b1.x; Bs[qq*8+5][r] = b1.y; Bs[qq*8+6][r] = b1.z; Bs[qq*8+7][r] = b1.w;
    __syncthreads();
#pragma unroll
    for (int kk = 0; kk < 16; ++kk) {
      float4 av0 = *(const float4*)&As[kk][ty*8];
      float4 av1 = *(const float4*)&As[kk][ty*8+4];
      float4 bv0 = *(const float4*)&Bs[kk][tx*8];
      float4 bv1 = *(const float4*)&Bs[kk][tx*8+4];
      float am[8] = {av0.x,av0.y,av0.z,av0.w,av1.x,av1.y,av1.z,av1.w};
      float bn[8] = {bv0.x,bv0.y,bv0.z,bv0.w,bv1.x,bv1.y,bv1.z,bv1.w};
#pragma unroll
      for (int i = 0; i < 8; ++i)
#pragma unroll
        for (int j = 0; j < 8; ++j)
          acc[i][j] = fmaf(am[i], bn[j], acc[i][j]);
    }
  }
  const float* bi_p = dir ? bihb : bihf;
  const float* bh_p = dir ? bhhb : bhhf;
  float bias[8];
#pragma unroll
  for (int j = 0; j < 8; ++j) { int n = n0 + tx*8 + j; bias[j] = bi_p[n] + bh_p[n]; }
  const int mb = m0 + ty * 8;
  const int tt = mb >> 5, bb = mb & 31;
#pragma unroll
  for (int j = 0; j < 8; ++j) {
    int n = n0 + tx*8 + j;
    float* dst = &xproj[((((size_t)dir*512 + tt)*1024) + n)*32 + bb];
    float4 s0 = make_float4(acc[0][j]+bias[j], acc[1][j]+bias[j], acc[2][j]+bias[j], acc[3][j]+bias[j]);
    float4 s1 = make_float4(acc[4][j]+bias[j], acc[5][j]+bias[j], acc[6][j]+bias[j], acc[7][j]+bias[j]);
    *(float4*)dst = s0;
    *(float4*)(dst + 4) = s1;
  }
}

// ---------------- K3: persistent bidirectional LSTM ----------------
// 64 WGs: dir = wg>>5, slice = wg&31 (8 j's). Sentinel protocol: hist slot s holds
// the h INPUT of step s (slot 0 unused; step 0 reads h0 directly). Producers write
// slot s+1 with fire-and-forget dwordx4 sc0sc1 stores (data IS the flag); consumers
// poll their column with 8 batched dwordx4 sc0sc1 loads until no word == sentinel.
// hist slot layout: [bh=b>>2][j][bl=b&3]  (8*256*4 floats = 32 KB)
__global__ __launch_bounds__(256, 1) void k_lstm(
    const float* __restrict__ whhf, const float* __restrict__ whhb,
    const float* __restrict__ h0, const float* __restrict__ c0,
    const float* __restrict__ xproj, float* __restrict__ hist)
{
  const int wg = blockIdx.x;           // 0..63
  const int dir = wg >> 5;
  const int slice = wg & 31;
  const int tid = threadIdx.x;
  const int rowg = tid >> 5;           // 0..7 => j_local
  const int bgrp = (tid >> 3) & 3;     // 0..3
  const int kgrp = tid & 7;            // 0..7
  const int jg = slice * 8 + rowg;     // 0..255
  const float* __restrict__ W = dir ? whhb : whhf;
  __shared__ float hl[32 * 256];

  // weights -> registers: w2[gate][kk2] covers k = kgrp*32 + 2*kk2 (+1)
  float2 w2[4][16];
#pragma unroll
  for (int g = 0; g < 4; ++g)
#pragma unroll
    for (int kk2 = 0; kk2 < 16; ++kk2)
      w2[g][kk2] = *(const float2*)&W[(size_t)(g*256 + jg)*256 + kgrp*32 + 2*kk2];

  // cell state (redundant across kgrp lanes)
  float cc[8];
#pragma unroll
  for (int bi = 0; bi < 8; ++bi)
    cc[bi] = c0[(size_t)(dir*32 + bgrp*8 + bi)*256 + jg];

  const int kk = tid & 31;
  const int base_col = tid & ~31;
  const int kw4 = 4*((tid >> 5) & 7);
  const int rot = (4*kgrp + 2*bgrp) & 31;
  float* const histd = hist + (size_t)dir * 513 * 8192;
  float hnew[8];

  for (int s = 0; s < 512; ++s) {
    const int t = dir ? (511 - s) : s;

    // (a) publish h from previous step into slot s (fire & forget)
    if (s > 0 && kgrp == 0) {
      float* dp  = histd + (size_t)s*8192 + ((size_t)(2*bgrp)*256 + jg)*4;
      float* dp2 = dp + 1024;
      vf4 s0; s0.x = hnew[0]; s0.y = hnew[1]; s0.z = hnew[2]; s0.w = hnew[3];
      vf4 s1; s1.x = hnew[4]; s1.y = hnew[5]; s1.z = hnew[6]; s1.w = hnew[7];
      asm volatile(
        "global_store_dwordx4 %0, %2, off sc0 sc1\n\t"
        "global_store_dwordx4 %1, %3, off sc0 sc1"
        :: "v"(dp), "v"(dp2), "v"(s0), "v"(s1) : "memory");
    }

    // (b) prefetch additive xproj term (only kgrp==0 lanes use it)
    float xpr[4][8];
    if (kgrp == 0) {
#pragma unroll
      for (int g = 0; g < 4; ++g) {
        const float* xp = &xproj[((((size_t)dir*512 + t)*1024) + g*256 + jg)*32 + bgrp*8];
        float4 x0 = *(const float4*)xp;
        float4 x1 = *(const float4*)(xp + 4);
        xpr[g][0]=x0.x; xpr[g][1]=x0.y; xpr[g][2]=x0.z; xpr[g][3]=x0.w;
        xpr[g][4]=x1.x; xpr[g][5]=x1.y; xpr[g][6]=x1.z; xpr[g][7]=x1.w;
      }
    }

    // (c) stage h input: column j = tid, all 32 b
    vf4 hv[8];
    if (s == 0) {
#pragma unroll
      for (int q = 0; q < 8; ++q)
#pragma unroll
        for (int bl = 0; bl < 4; ++bl)
          hv[q][bl] = h0[(size_t)(dir*32 + 4*q + bl)*256 + tid];
    } else {
      const float* sp = histd + (size_t)s*8192 + (size_t)tid*4;
      const float* p0 = sp;
      const float* p1 = sp + 1024;
      const float* p2 = sp + 2048;
      const float* p3 = sp + 3072;
      const float* p4 = sp + 4096;
      const float* p5 = sp + 5120;
      const float* p6 = sp + 6144;
      const float* p7 = sp + 7168;
      while (true) {
        asm volatile(
          "global_load_dwordx4 %0, %8, off sc0 sc1\n\t"
          "global_load_dwordx4 %1, %9, off sc0 sc1\n\t"
          "global_load_dwordx4 %2, %10, off sc0 sc1\n\t"
          "global_load_dwordx4 %3, %11, off sc0 sc1\n\t"
          "global_load_dwordx4 %4, %12, off sc0 sc1\n\t"
          "global_load_dwordx4 %5, %13, off sc0 sc1\n\t"
          "global_load_dwordx4 %6, %14, off sc0 sc1\n\t"
          "global_load_dwordx4 %7, %15, off sc0 sc1\n\t"
          "s_waitcnt vmcnt(0)"
          : "=&v"(hv[0]), "=&v"(hv[1]), "=&v"(hv[2]), "=&v"(hv[3]),
            "=&v"(hv[4]), "=&v"(hv[5]), "=&v"(hv[6]), "=&v"(hv[7])
          : "v"(p0), "v"(p1), "v"(p2), "v"(p3),
            "v"(p4), "v"(p5), "v"(p6), "v"(p7)
          : "memory");
        unsigned z = 0xFFFFFFFFu;
#pragma unroll
        for (int q = 0; q < 8; ++q)
#pragma unroll
          for (int bl = 0; bl < 4; ++bl)
            z = um(z, __float_as_uint(hv[q][bl]) ^ SENTU);
        if (z) break;
        __builtin_amdgcn_s_sleep(1);
      }
    }

    // (d) scatter to LDS with rotation swizzle (identical hl contents as verified)
#pragma unroll
    for (int q = 0; q < 8; ++q) {
      const int rwq = (kw4 + 2*((q >> 1) & 3)) & 31;
      const int col = base_col + ((kk + rwq) & 31);
#pragma unroll
      for (int bl = 0; bl < 4; ++bl)
        hl[(4*q + bl)*256 + col] = hv[q][bl];
    }
    __syncthreads();

    // (e) gates partial sums over our 32-k slice
    float acc[4][8];
#pragma unroll
    for (int g = 0; g < 4; ++g)
#pragma unroll
      for (int bi = 0; bi < 8; ++bi) acc[g][bi] = 0.f;

    const int hbase = kgrp * 32;
#pragma unroll
    for (int kk2 = 0; kk2 < 16; ++kk2) {
      const int idx = hbase + ((2*kk2 + rot) & 31);
      float2 h2[8];
#pragma unroll
      for (int bi = 0; bi < 8; ++bi)
        h2[bi] = *(const float2*)&hl[(bgrp*8 + bi)*256 + idx];
#pragma unroll
      for (int g = 0; g < 4; ++g)
#pragma unroll
        for (int bi = 0; bi < 8; ++bi) {
          acc[g][bi] = fmaf(w2[g][kk2].x, h2[bi].x, acc[g][bi]);
          acc[g][bi] = fmaf(w2[g][kk2].y, h2[bi].y, acc[g][bi]);
        }
    }

    // xproj term once (kgrp==0), then butterfly-reduce over the 8 kgrp lanes
    if (kgrp == 0) {
#pragma unroll
      for (int g = 0; g < 4; ++g)
#pragma unroll
        for (int bi = 0; bi < 8; ++bi) acc[g][bi] += xpr[g][bi];
    }
#pragma unroll
    for (int g = 0; g < 4; ++g)
#pragma unroll
      for (int bi = 0; bi < 8; ++bi) {
        float v = acc[g][bi];
        v += __shfl_xor(v, 1, 64);
        v += __shfl_xor(v, 2, 64);
        v += __shfl_xor(v, 4, 64);
        acc[g][bi] = v;
      }

    // LSTM cell update (PyTorch gate order i,f,g,o)
#pragma unroll
    for (int bi = 0; bi < 8; ++bi) {
      float ig = fsig(acc[0][bi]);
      float fg = fsig(acc[1][bi]);
      float gg = ftanh(acc[2][bi]);
      float og = fsig(acc[3][bi]);
      cc[bi] = fg * cc[bi] + ig * gg;
      hnew[bi] = og * ftanh(cc[bi]);
    }
    __syncthreads();   // protect hl before next scatter
  }

  // epilogue: publish final h into slot 512 (k_feats input)
  if (kgrp == 0) {
    float* dp  = histd + (size_t)512*8192 + ((size_t)(2*bgrp)*256 + jg)*4;
    float* dp2 = dp + 1024;
    vf4 s0; s0.x = hnew[0]; s0.y = hnew[1]; s0.z = hnew[2]; s0.w = hnew[3];
    vf4 s1; s1.x = hnew[4]; s1.y = hnew[5]; s1.z = hnew[6]; s1.w = hnew[7];
    asm volatile(
      "global_store_dwordx4 %0, %2, off sc0 sc1\n\t"
      "global_store_dwordx4 %1, %3, off sc0 sc1"
      :: "v"(dp), "v"(dp2), "v"(s0), "v"(s1) : "memory");
  }
}

// ---------------- K4: feats = hs @ w_out^T + b_out (reads hist) ----------------
// fwd h-output at time t = hist[0][t+1]; bwd h-output at time t = hist[1][512-t]
__global__ __launch_bounds__(256) void k_feats(
    const float* __restrict__ hist, const float* __restrict__ wout,
    const float* __restrict__ bout, float* __restrict__ feats)
{
  const int t = blockIdx.x;
  const int tid = threadIdx.x;
  __shared__ float hlds[32 * 516];
#pragma unroll
  for (int dir = 0; dir < 2; ++dir) {
    const int slot = dir ? (512 - t) : (t + 1);
    const float* sp = hist + ((size_t)dir*513 + slot)*8192;
#pragma unroll
    for (int q = 0; q < 8; ++q) {
      vf4 v = *(const vf4*)&sp[(size_t)(q*256 + tid)*4];
      float* d = &hlds[(4*q)*516 + dir*256 + tid];
      d[0*516] = v.x; d[1*516] = v.y; d[2*516] = v.z; d[3*516] = v.w;
    }
  }
  __syncthreads();
  const int b = tid >> 3, ks = tid & 7;
#pragma unroll
  for (int kt = 0; kt < 3; ++kt) {
    int k = kt * 8 + ks;
    float acc = bout[k];
    const float* wr = wout + (size_t)k * 512;
#pragma unroll 8
    for (int kk = 0; kk < 512; kk += 4) {
      float4 h4 = *(const float4*)&hlds[b * 516 + kk];
      float4 w4 = *(const float4*)&wr[kk];
      acc += h4.x*w4.x + h4.y*w4.y + h4.z*w4.z + h4.w*w4.w;
    }
    feats[((size_t)t * 32 + b) * 24 + k] = acc;
  }
}

// ---------------- K5: Viterbi + backtrace, one wave per batch element ----------------
__global__ __launch_bounds__(64) void k_viterbi(
    const float* __restrict__ feats, const float* __restrict__ trans,
    float* __restrict__ out)
{
  const int b = blockIdx.x;      // 0..31
  const int lane = threadIdx.x;  // 0..63 ; active tag lane if <24
  const int k = lane;
  __shared__ float fvl[2][32];
  __shared__ float pathb[512];
  __shared__ unsigned char bcol[512 * 24];
  float trr[24];
  if (k < 24) {
#pragma unroll
    for (int pv = 0; pv < 24; ++pv) trr[pv] = trans[k * 24 + pv];
  }
  if (k < 32) fvl[0][k] = (k == START_TAG) ? 0.f : NEGV;
  if (k < 32) fvl[1][k] = NEGV;
  __syncthreads();
  float fcur = (k < 24) ? feats[b * 24 + k] : 0.f;
  int q = 0;
  for (int t = 0; t < 512; ++t) {
    float fnext = (t < 511 && k < 24) ? feats[(size_t)(t + 1) * 768 + b * 24 + k] : 0.f;
    float fvp[24];
    {
      const float4* fp4 = (const float4*)&fvl[q][0];
#pragma unroll
      for (int i = 0; i < 6; ++i) {
        float4 v = fp4[i];
        fvp[i*4+0] = v.x; fvp[i*4+1] = v.y; fvp[i*4+2] = v.z; fvp[i*4+3] = v.w;
      }
    }
    float best = -3.4e38f; int bp = 0;
#pragma unroll
    for (int pv = 0; pv < 24; ++pv) {
      float v = fvp[pv] + trr[pv];
      if (v > best) { best = v; bp = pv; }   // strict > : first-max, matches argmax
    }
    if (k < 24) {
      fvl[q ^ 1][k] = best + fcur;
      bcol[t * 24 + k] = (unsigned char)bp;
    }
    fcur = fnext;
    q ^= 1;
    __syncthreads();
  }
  if (lane == 0) {
    float best = -3.4e38f; int bt = 0;
#pragma unroll
    for (int kk = 0; kk < 24; ++kk) {
      float v = fvl[q][kk] + trans[STOP_TAG * 24 + kk];
      if (v > best) { best = v; bt = kk; }
    }
    out[b] = best;
    pathb[511] = (float)bt;
    int tag = bt;
    for (int t = 511; t >= 1; --t) {
      tag = bcol[t * 24 + tag];
      pathb[t - 1] = (float)tag;
    }
  }
  __syncthreads();
#pragma unroll
  for (int it = 0; it < 8; ++it)
    out[32 + (size_t)b * 512 + it * 64 + lane] = pathb[it * 64 + lane];
}

// ---------------- launch ----------------
extern "C" void kernel_launch(void* const* d_in, const int* in_sizes, int n_in,
                              void* d_out, int out_size, void* d_ws, size_t ws_size,
                              hipStream_t stream) {
  (void)in_sizes; (void)n_in; (void)out_size; (void)ws_size;
  const int*   sent = (const int*)d_in[0];
  const float* emb  = (const float*)d_in[1];
  const float* wihf = (const float*)d_in[2];
  const float* whhf = (const float*)d_in[3];
  const float* bihf = (const float*)d_in[4];
  const float* bhhf = (const float*)d_in[5];
  const float* wihb = (const float*)d_in[6];
  const float* whhb = (const float*)d_in[7];
  const float* bihb = (const float*)d_in[8];
  const float* bhhb = (const float*)d_in[9];
  const float* wout = (const float*)d_in[10];
  const float* bout = (const float*)d_in[11];
  const float* trans= (const float*)d_in[12];
  const float* h0   = (const float*)d_in[13];
  const float* c0   = (const float*)d_in[14];

  float* ws     = (float*)d_ws;
  float* xproj  = ws + XPROJ_OFF;
  float* feats  = ws + FEATS_OFF;
  float* hist   = ws + HIST_OFF;

  k_fill<<<(int)((HIST_ELEMS + 255) / 256), 256, 0, stream>>>((unsigned*)hist, (int)HIST_ELEMS);
  k_xproj<<<dim3(128, 8, 2), 256, 0, stream>>>(sent, emb, wihf, wihb,
                                               bihf, bhhf, bihb, bhhb, xproj);
  k_lstm<<<64, 256, 0, stream>>>(whhf, whhb, h0, c0, xproj, hist);
  k_feats<<<512, 256, 0, stream>>>(hist, wout, bout, feats);
  k_viterbi<<<32, 64, 0, stream>>>(feats, trans, (float*)d_out);
}

// Round 4
// 4339.106 us; speedup vs baseline: 2.0394x; 1.1399x over previous
//
#include <hip/hip_runtime.h>

// ---------------- constants ----------------
#define T_LEN 512
#define BATCH 32
#define HDIR  256
#define KTAG  24
#define START_TAG 22
#define STOP_TAG  23
#define NEGV  (-10000.0f)
#define SENTU 0x7FC0DEADu   // NaN payload; h = sig*tanh can never be NaN

typedef float vf4 __attribute__((ext_vector_type(4)));

// workspace layout (float elements)
#define XPROJ_OFF   0ull
#define XPROJ_ELEMS (2ull*512*1024*32)            // [dir][t][row1024][b32]
#define FEATS_OFF   (XPROJ_OFF + XPROJ_ELEMS)     // [t][b][24]
#define FEATS_ELEMS (512ull*32*24)
#define HIST_OFF    (FEATS_OFF + FEATS_ELEMS)     // [dir][slot513][bh8][j256][bl4]
#define HIST_ELEMS  (2ull*513*8192)

// lgkm-only barrier: LDS producer/consumer sync WITHOUT draining vmcnt --
// publish stores and xproj prefetch loads stay in flight across it.
#define BARRIER_LGKM() asm volatile("s_waitcnt lgkmcnt(0)\n\ts_barrier" ::: "memory")

__device__ __forceinline__ float fsig(float x) {
  return __builtin_amdgcn_rcpf(1.0f + __expf(-x));
}
__device__ __forceinline__ float ftanh(float x) {
  return 2.0f * __builtin_amdgcn_rcpf(1.0f + __expf(-2.0f * x)) - 1.0f;
}
__device__ __forceinline__ unsigned um(unsigned a, unsigned b) { return a < b ? a : b; }

// ---------------- K1: sentinel-fill hist (direct to MALL via sc0 sc1) ----------------
__global__ void k_fill(float* __restrict__ p, int n4) {
  int i = blockIdx.x * blockDim.x + threadIdx.x;
  if (i < n4) {
    float* dst = p + (size_t)i * 4;
    const float sv = __uint_as_float(SENTU);
    vf4 v; v.x = sv; v.y = sv; v.z = sv; v.w = sv;
    asm volatile("global_store_dwordx4 %0, %1, off sc0 sc1"
                 :: "v"(dst), "v"(v) : "memory");
  }
}

// ---------------- K2: embedding gather + input projection GEMM ----------------
// xproj[dir][t][row][b] = emb[sent[b][t]] . w_ih_dir[row] + b_ih[row] + b_hh[row]
__global__ __launch_bounds__(256) void k_xproj(
    const int* __restrict__ sent, const float* __restrict__ emb,
    const float* __restrict__ wf, const float* __restrict__ wb,
    const float* __restrict__ bihf, const float* __restrict__ bhhf,
    const float* __restrict__ bihb, const float* __restrict__ bhhb,
    float* __restrict__ xproj)
{
  __shared__ float As[16][132];   // [k][m]
  __shared__ float Bs[16][132];   // [k][n]
  __shared__ int sid[128];
  const int tid = threadIdx.x;
  const int m0 = blockIdx.x * 128;
  const int n0 = blockIdx.y * 128;
  const int dir = blockIdx.z;
  const float* __restrict__ W = dir ? wb : wf;
  if (tid < 128) {
    int m = m0 + tid;                       // m = t*32 + b
    sid[tid] = sent[(m & 31) * 512 + (m >> 5)];
  }
  __syncthreads();
  float acc[8][8];
#pragma unroll
  for (int i = 0; i < 8; ++i)
#pragma unroll
    for (int j = 0; j < 8; ++j) acc[i][j] = 0.f;
  const int r = tid >> 1, qq = tid & 1;
  const int ty = tid >> 4, tx = tid & 15;
  for (int k0 = 0; k0 < 256; k0 += 16) {
    const float* ap = &emb[(size_t)sid[r] * 256 + k0 + qq * 8];
    const float* bp = &W[(size_t)(n0 + r) * 256 + k0 + qq * 8];
    float4 a0 = *(const float4*)ap;
    float4 a1 = *(const float4*)(ap + 4);
    float4 b0 = *(const float4*)bp;
    float4 b1 = *(const float4*)(bp + 4);
    __syncthreads();
    As[qq*8+0][r] = a0.x; As[qq*8+1][r] = a0.y; As[qq*8+2][r] = a0.z; As[qq*8+3][r] = a0.w;
    As[qq*8+4][r] = a1.x; As[qq*8+5][r] = a1.y; As[qq*8+6][r] = a1.z; As[qq*8+7][r] = a1.w;
    Bs[qq*8+0][r] = b0.x; Bs[qq*8+1][r] = b0.y; Bs[qq*8+2][r] = b0.z; Bs[qq*8+3][r] = b0.w;
    Bs[qq*8+4][r] = b1.x; Bs[qq*8+5][r] = b1.y; Bs[qq*8+6][r] = b1.z; Bs[qq*8+7][r] = b1.w;
    __syncthreads();
#pragma unroll
    for (int kk = 0; kk < 16; ++kk) {
      float4 av0 = *(const float4*)&As[kk][ty*8];
      float4 av1 = *(const float4*)&As[kk][ty*8+4];
      float4 bv0 = *(const float4*)&Bs[kk][tx*8];
      float4 bv1 = *(const float4*)&Bs[kk][tx*8+4];
      float am[8] = {av0.x,av0.y,av0.z,av0.w,av1.x,av1.y,av1.z,av1.w};
      float bn[8] = {bv0.x,bv0.y,bv0.z,bv0.w,bv1.x,bv1.y,bv1.z,bv1.w};
#pragma unroll
      for (int i = 0; i < 8; ++i)
#pragma unroll
        for (int j = 0; j < 8; ++j)
          acc[i][j] = fmaf(am[i], bn[j], acc[i][j]);
    }
  }
  const float* bi_p = dir ? bihb : bihf;
  const float* bh_p = dir ? bhhb : bhhf;
  float bias[8];
#pragma unroll
  for (int j = 0; j < 8; ++j) { int n = n0 + tx*8 + j; bias[j] = bi_p[n] + bh_p[n]; }
  const int mb = m0 + ty * 8;
  const int tt = mb >> 5, bb = mb & 31;
#pragma unroll
  for (int j = 0; j < 8; ++j) {
    int n = n0 + tx*8 + j;
    float* dst = &xproj[((((size_t)dir*512 + tt)*1024) + n)*32 + bb];
    float4 s0 = make_float4(acc[0][j]+bias[j], acc[1][j]+bias[j], acc[2][j]+bias[j], acc[3][j]+bias[j]);
    float4 s1 = make_float4(acc[4][j]+bias[j], acc[5][j]+bias[j], acc[6][j]+bias[j], acc[7][j]+bias[j]);
    *(float4*)dst = s0;
    *(float4*)(dst + 4) = s1;
  }
}

// ---------------- K3: persistent bidirectional LSTM ----------------
// 64 WGs: dir = wg>>5, slice = wg&31 (8 j's). Sentinel protocol: hist slot s holds
// the h INPUT of step s (slot 0 unused; step 0 reads h0 directly). Producers write
// slot s+1 right after the cell update with fire-and-forget dwordx4 sc0sc1 stores
// (data IS the flag); consumers poll their column with 8 batched dwordx4 sc0sc1
// loads until no word == sentinel. Barriers are lgkm-only (publish stores / xpr
// prefetch loads ride across them); the next poll's vmcnt(0) retires the publish
// before hnew is overwritten (WAR-safe).
// hist slot layout: [bh=b>>2][j][bl=b&3]  (8*256*4 floats = 32 KB)
__global__ __launch_bounds__(256, 1) void k_lstm(
    const float* __restrict__ whhf, const float* __restrict__ whhb,
    const float* __restrict__ h0, const float* __restrict__ c0,
    const float* __restrict__ xproj, float* __restrict__ hist)
{
  const int wg = blockIdx.x;           // 0..63
  const int dir = wg >> 5;
  const int slice = wg & 31;
  const int tid = threadIdx.x;
  const int rowg = tid >> 5;           // 0..7 => j_local
  const int bgrp = (tid >> 3) & 3;     // 0..3
  const int kgrp = tid & 7;            // 0..7
  const int jg = slice * 8 + rowg;     // 0..255
  const float* __restrict__ W = dir ? whhb : whhf;
  __shared__ float hl[32 * 256];

  // weights -> registers: w2[gate][kk2] covers k = kgrp*32 + 2*kk2 (+1)
  float2 w2[4][16];
#pragma unroll
  for (int g = 0; g < 4; ++g)
#pragma unroll
    for (int kk2 = 0; kk2 < 16; ++kk2)
      w2[g][kk2] = *(const float2*)&W[(size_t)(g*256 + jg)*256 + kgrp*32 + 2*kk2];

  // cell state (redundant across kgrp lanes)
  float cc[8];
#pragma unroll
  for (int bi = 0; bi < 8; ++bi)
    cc[bi] = c0[(size_t)(dir*32 + bgrp*8 + bi)*256 + jg];

  const int kk = tid & 31;
  const int base_col = tid & ~31;
  const int kw4 = 4*((tid >> 5) & 7);
  const int rot = (4*kgrp + 2*bgrp) & 31;
  float* const histd = hist + (size_t)dir * 513 * 8192;
  float hnew[8];

  for (int s = 0; s < 512; ++s) {
    const int t = dir ? (511 - s) : s;

    // (a) obtain h input: column j = tid, all 32 b
    vf4 hv[8];
    if (s == 0) {
#pragma unroll
      for (int q = 0; q < 8; ++q)
#pragma unroll
        for (int bl = 0; bl < 4; ++bl)
          hv[q][bl] = h0[(size_t)(dir*32 + 4*q + bl)*256 + tid];
    } else {
      const float* sp = histd + (size_t)s*8192 + (size_t)tid*4;
      const float* p0 = sp;
      const float* p1 = sp + 1024;
      const float* p2 = sp + 2048;
      const float* p3 = sp + 3072;
      const float* p4 = sp + 4096;
      const float* p5 = sp + 5120;
      const float* p6 = sp + 6144;
      const float* p7 = sp + 7168;
      while (true) {
        asm volatile(
          "global_load_dwordx4 %0, %8, off sc0 sc1\n\t"
          "global_load_dwordx4 %1, %9, off sc0 sc1\n\t"
          "global_load_dwordx4 %2, %10, off sc0 sc1\n\t"
          "global_load_dwordx4 %3, %11, off sc0 sc1\n\t"
          "global_load_dwordx4 %4, %12, off sc0 sc1\n\t"
          "global_load_dwordx4 %5, %13, off sc0 sc1\n\t"
          "global_load_dwordx4 %6, %14, off sc0 sc1\n\t"
          "global_load_dwordx4 %7, %15, off sc0 sc1\n\t"
          "s_waitcnt vmcnt(0)"
          : "=&v"(hv[0]), "=&v"(hv[1]), "=&v"(hv[2]), "=&v"(hv[3]),
            "=&v"(hv[4]), "=&v"(hv[5]), "=&v"(hv[6]), "=&v"(hv[7])
          : "v"(p0), "v"(p1), "v"(p2), "v"(p3),
            "v"(p4), "v"(p5), "v"(p6), "v"(p7)
          : "memory");
        unsigned z = 0xFFFFFFFFu;
#pragma unroll
        for (int q = 0; q < 8; ++q)
#pragma unroll
          for (int bl = 0; bl < 4; ++bl)
            z = um(z, __float_as_uint(hv[q][bl]) ^ SENTU);
        if (z) break;
        __builtin_amdgcn_s_sleep(1);
      }
    }

    // (b) xproj prefetch for THIS step, issued AFTER the poll so the poll's
    // vmcnt(0) never drains it; consumed after the FMA block (~1.2us cover).
    float xpr[4][8];
    if (kgrp == 0) {
#pragma unroll
      for (int g = 0; g < 4; ++g) {
        const float* xp = &xproj[((((size_t)dir*512 + t)*1024) + g*256 + jg)*32 + bgrp*8];
        float4 x0 = *(const float4*)xp;
        float4 x1 = *(const float4*)(xp + 4);
        xpr[g][0]=x0.x; xpr[g][1]=x0.y; xpr[g][2]=x0.z; xpr[g][3]=x0.w;
        xpr[g][4]=x1.x; xpr[g][5]=x1.y; xpr[g][6]=x1.z; xpr[g][7]=x1.w;
      }
    }

    // (c) scatter to LDS with rotation swizzle (identical hl contents as verified)
#pragma unroll
    for (int q = 0; q < 8; ++q) {
      const int rwq = (kw4 + 2*((q >> 1) & 3)) & 31;
      const int col = base_col + ((kk + rwq) & 31);
#pragma unroll
      for (int bl = 0; bl < 4; ++bl)
        hl[(4*q + bl)*256 + col] = hv[q][bl];
    }
    BARRIER_LGKM();

    // (d) gates partial sums over our 32-k slice
    float acc[4][8];
#pragma unroll
    for (int g = 0; g < 4; ++g)
#pragma unroll
      for (int bi = 0; bi < 8; ++bi) acc[g][bi] = 0.f;

    const int hbase = kgrp * 32;
#pragma unroll
    for (int kk2 = 0; kk2 < 16; ++kk2) {
      const int idx = hbase + ((2*kk2 + rot) & 31);
      float2 h2[8];
#pragma unroll
      for (int bi = 0; bi < 8; ++bi)
        h2[bi] = *(const float2*)&hl[(bgrp*8 + bi)*256 + idx];
#pragma unroll
      for (int g = 0; g < 4; ++g)
#pragma unroll
        for (int bi = 0; bi < 8; ++bi) {
          acc[g][bi] = fmaf(w2[g][kk2].x, h2[bi].x, acc[g][bi]);
          acc[g][bi] = fmaf(w2[g][kk2].y, h2[bi].y, acc[g][bi]);
        }
    }

    // (e) xproj term once (kgrp==0), then butterfly-reduce over the 8 kgrp lanes
    if (kgrp == 0) {
#pragma unroll
      for (int g = 0; g < 4; ++g)
#pragma unroll
        for (int bi = 0; bi < 8; ++bi) acc[g][bi] += xpr[g][bi];
    }
#pragma unroll
    for (int g = 0; g < 4; ++g)
#pragma unroll
      for (int bi = 0; bi < 8; ++bi) {
        float v = acc[g][bi];
        v += __shfl_xor(v, 1, 64);
        v += __shfl_xor(v, 2, 64);
        v += __shfl_xor(v, 4, 64);
        acc[g][bi] = v;
      }

    // (f) LSTM cell update (PyTorch gate order i,f,g,o)
#pragma unroll
    for (int bi = 0; bi < 8; ++bi) {
      float ig = fsig(acc[0][bi]);
      float fg = fsig(acc[1][bi]);
      float gg = ftanh(acc[2][bi]);
      float og = fsig(acc[3][bi]);
      cc[bi] = fg * cc[bi] + ig * gg;
      hnew[bi] = og * ftanh(cc[bi]);
    }

    // (g) publish h into slot s+1 immediately (fire & forget; rides across the
    // barrier below; next poll's vmcnt(0) retires it before hnew is rewritten)
    if (kgrp == 0) {
      float* dp  = histd + (size_t)(s + 1)*8192 + ((size_t)(2*bgrp)*256 + jg)*4;
      float* dp2 = dp + 1024;
      vf4 s0; s0.x = hnew[0]; s0.y = hnew[1]; s0.z = hnew[2]; s0.w = hnew[3];
      vf4 s1; s1.x = hnew[4]; s1.y = hnew[5]; s1.z = hnew[6]; s1.w = hnew[7];
      asm volatile(
        "global_store_dwordx4 %0, %2, off sc0 sc1\n\t"
        "global_store_dwordx4 %1, %3, off sc0 sc1"
        :: "v"(dp), "v"(dp2), "v"(s0), "v"(s1) : "memory");
    }

    BARRIER_LGKM();   // protect hl before next scatter (no vmcnt drain)
  }
}

// ---------------- K4: feats = hs @ w_out^T + b_out (reads hist) ----------------
// fwd h-output at time t = hist[0][t+1]; bwd h-output at time t = hist[1][512-t]
__global__ __launch_bounds__(256) void k_feats(
    const float* __restrict__ hist, const float* __restrict__ wout,
    const float* __restrict__ bout, float* __restrict__ feats)
{
  const int t = blockIdx.x;
  const int tid = threadIdx.x;
  __shared__ float hlds[32 * 516];
#pragma unroll
  for (int dir = 0; dir < 2; ++dir) {
    const int slot = dir ? (512 - t) : (t + 1);
    const float* sp = hist + ((size_t)dir*513 + slot)*8192;
#pragma unroll
    for (int q = 0; q < 8; ++q) {
      vf4 v = *(const vf4*)&sp[(size_t)(q*256 + tid)*4];
      float* d = &hlds[(4*q)*516 + dir*256 + tid];
      d[0*516] = v.x; d[1*516] = v.y; d[2*516] = v.z; d[3*516] = v.w;
    }
  }
  __syncthreads();
  const int b = tid >> 3, ks = tid & 7;
#pragma unroll
  for (int kt = 0; kt < 3; ++kt) {
    int k = kt * 8 + ks;
    float acc = bout[k];
    const float* wr = wout + (size_t)k * 512;
#pragma unroll 8
    for (int kk = 0; kk < 512; kk += 4) {
      float4 h4 = *(const float4*)&hlds[b * 516 + kk];
      float4 w4 = *(const float4*)&wr[kk];
      acc += h4.x*w4.x + h4.y*w4.y + h4.z*w4.z + h4.w*w4.w;
    }
    feats[((size_t)t * 32 + b) * 24 + k] = acc;
  }
}

// ---------------- K5: Viterbi + backtrace, one wave per batch element ----------------
__global__ __launch_bounds__(64) void k_viterbi(
    const float* __restrict__ feats, const float* __restrict__ trans,
    float* __restrict__ out)
{
  const int b = blockIdx.x;      // 0..31
  const int lane = threadIdx.x;  // 0..63 ; active tag lane if <24
  const int k = lane;
  __shared__ float fvl[2][32];
  __shared__ float pathb[512];
  __shared__ unsigned char bcol[512 * 24];
  float trr[24];
  if (k < 24) {
#pragma unroll
    for (int pv = 0; pv < 24; ++pv) trr[pv] = trans[k * 24 + pv];
  }
  if (k < 32) fvl[0][k] = (k == START_TAG) ? 0.f : NEGV;
  if (k < 32) fvl[1][k] = NEGV;
  __syncthreads();
  float fcur = (k < 24) ? feats[b * 24 + k] : 0.f;
  int q = 0;
  for (int t = 0; t < 512; ++t) {
    float fnext = (t < 511 && k < 24) ? feats[(size_t)(t + 1) * 768 + b * 24 + k] : 0.f;
    float fvp[24];
    {
      const float4* fp4 = (const float4*)&fvl[q][0];
#pragma unroll
      for (int i = 0; i < 6; ++i) {
        float4 v = fp4[i];
        fvp[i*4+0] = v.x; fvp[i*4+1] = v.y; fvp[i*4+2] = v.z; fvp[i*4+3] = v.w;
      }
    }
    float best = -3.4e38f; int bp = 0;
#pragma unroll
    for (int pv = 0; pv < 24; ++pv) {
      float v = fvp[pv] + trr[pv];
      if (v > best) { best = v; bp = pv; }   // strict > : first-max, matches argmax
    }
    if (k < 24) {
      fvl[q ^ 1][k] = best + fcur;
      bcol[t * 24 + k] = (unsigned char)bp;
    }
    fcur = fnext;
    q ^= 1;
    __syncthreads();
  }
  if (lane == 0) {
    float best = -3.4e38f; int bt = 0;
#pragma unroll
    for (int kk = 0; kk < 24; ++kk) {
      float v = fvl[q][kk] + trans[STOP_TAG * 24 + kk];
      if (v > best) { best = v; bt = kk; }
    }
    out[b] = best;
    pathb[511] = (float)bt;
    int tag = bt;
    for (int t = 511; t >= 1; --t) {
      tag = bcol[t * 24 + tag];
      pathb[t - 1] = (float)tag;
    }
  }
  __syncthreads();
#pragma unroll
  for (int it = 0; it < 8; ++it)
    out[32 + (size_t)b * 512 + it * 64 + lane] = pathb[it * 64 + lane];
}

// ---------------- launch ----------------
extern "C" void kernel_launch(void* const* d_in, const int* in_sizes, int n_in,
                              void* d_out, int out_size, void* d_ws, size_t ws_size,
                              hipStream_t stream) {
  (void)in_sizes; (void)n_in; (void)out_size; (void)ws_size;
  const int*   sent = (const int*)d_in[0];
  const float* emb  = (const float*)d_in[1];
  const float* wihf = (const float*)d_in[2];
  const float* whhf = (const float*)d_in[3];
  const float* bihf = (const float*)d_in[4];
  const float* bhhf = (const float*)d_in[5];
  const float* wihb = (const float*)d_in[6];
  const float* whhb = (const float*)d_in[7];
  const float* bihb = (const float*)d_in[8];
  const float* bhhb = (const float*)d_in[9];
  const float* wout = (const float*)d_in[10];
  const float* bout = (const float*)d_in[11];
  const float* trans= (const float*)d_in[12];
  const float* h0   = (const float*)d_in[13];
  const float* c0   = (const float*)d_in[14];

  float* ws     = (float*)d_ws;
  float* xproj  = ws + XPROJ_OFF;
  float* feats  = ws + FEATS_OFF;
  float* hist   = ws + HIST_OFF;

  const int n4 = (int)(HIST_ELEMS / 4);   // 2,101,248 dwordx4 stores, exact cover
  k_fill<<<(n4 + 255) / 256, 256, 0, stream>>>(hist, n4);
  k_xproj<<<dim3(128, 8, 2), 256, 0, stream>>>(sent, emb, wihf, wihb,
                                               bihf, bhhf, bihb, bhhb, xproj);
  k_lstm<<<64, 256, 0, stream>>>(whhf, whhb, h0, c0, xproj, hist);
  k_feats<<<512, 256, 0, stream>>>(hist, wout, bout, feats);
  k_viterbi<<<32, 64, 0, stream>>>(feats, trans, (float*)d_out);
}

// Round 5
// 4291.959 us; speedup vs baseline: 2.0618x; 1.0110x over previous
//
#include <hip/hip_runtime.h>

// ---------------- constants ----------------
#define T_LEN 512
#define BATCH 32
#define HDIR  256
#define KTAG  24
#define START_TAG 22
#define STOP_TAG  23
#define NEGV  (-10000.0f)
#define SENTU 0x7FC0DEADu   // NaN payload; h = sig*tanh can never be NaN

typedef float vf4 __attribute__((ext_vector_type(4)));

// workspace layout (float elements)
#define XPROJ_OFF   0ull
#define XPROJ_ELEMS (2ull*512*1024*32)            // [dir][t][row1024][b32]
#define FEATS_OFF   (XPROJ_OFF + XPROJ_ELEMS)     // [t][b][24]
#define FEATS_ELEMS (512ull*32*24)
#define HIST_OFF    (FEATS_OFF + FEATS_ELEMS)     // [dir][slot513][bh8][j256][bl4]
#define HIST_ELEMS  (2ull*513*8192)

// lgkm-only barrier: LDS producer/consumer sync WITHOUT draining vmcnt --
// publish stores and xproj prefetch loads stay in flight across it.
#define BARRIER_LGKM() asm volatile("s_waitcnt lgkmcnt(0)\n\ts_barrier" ::: "memory")

__device__ __forceinline__ float fsig(float x) {
  return __builtin_amdgcn_rcpf(1.0f + __expf(-x));
}
__device__ __forceinline__ float ftanh(float x) {
  return 2.0f * __builtin_amdgcn_rcpf(1.0f + __expf(-2.0f * x)) - 1.0f;
}
__device__ __forceinline__ unsigned um(unsigned a, unsigned b) { return a < b ? a : b; }

// ---------------- K1: sentinel-fill hist (direct to MALL via sc0 sc1) ----------------
__global__ void k_fill(float* __restrict__ p, int n4) {
  int i = blockIdx.x * blockDim.x + threadIdx.x;
  if (i < n4) {
    float* dst = p + (size_t)i * 4;
    const float sv = __uint_as_float(SENTU);
    vf4 v; v.x = sv; v.y = sv; v.z = sv; v.w = sv;
    asm volatile("global_store_dwordx4 %0, %1, off sc0 sc1"
                 :: "v"(dst), "v"(v) : "memory");
  }
}

// ---------------- K2: embedding gather + input projection GEMM ----------------
// xproj[dir][t][row][b] = emb[sent[b][t]] . w_ih_dir[row] + b_ih[row] + b_hh[row]
__global__ __launch_bounds__(256) void k_xproj(
    const int* __restrict__ sent, const float* __restrict__ emb,
    const float* __restrict__ wf, const float* __restrict__ wb,
    const float* __restrict__ bihf, const float* __restrict__ bhhf,
    const float* __restrict__ bihb, const float* __restrict__ bhhb,
    float* __restrict__ xproj)
{
  __shared__ float As[16][132];   // [k][m]
  __shared__ float Bs[16][132];   // [k][n]
  __shared__ int sid[128];
  const int tid = threadIdx.x;
  const int m0 = blockIdx.x * 128;
  const int n0 = blockIdx.y * 128;
  const int dir = blockIdx.z;
  const float* __restrict__ W = dir ? wb : wf;
  if (tid < 128) {
    int m = m0 + tid;                       // m = t*32 + b
    sid[tid] = sent[(m & 31) * 512 + (m >> 5)];
  }
  __syncthreads();
  float acc[8][8];
#pragma unroll
  for (int i = 0; i < 8; ++i)
#pragma unroll
    for (int j = 0; j < 8; ++j) acc[i][j] = 0.f;
  const int r = tid >> 1, qq = tid & 1;
  const int ty = tid >> 4, tx = tid & 15;
  for (int k0 = 0; k0 < 256; k0 += 16) {
    const float* ap = &emb[(size_t)sid[r] * 256 + k0 + qq * 8];
    const float* bp = &W[(size_t)(n0 + r) * 256 + k0 + qq * 8];
    float4 a0 = *(const float4*)ap;
    float4 a1 = *(const float4*)(ap + 4);
    float4 b0 = *(const float4*)bp;
    float4 b1 = *(const float4*)(bp + 4);
    __syncthreads();
    As[qq*8+0][r] = a0.x; As[qq*8+1][r] = a0.y; As[qq*8+2][r] = a0.z; As[qq*8+3][r] = a0.w;
    As[qq*8+4][r] = a1.x; As[qq*8+5][r] = a1.y; As[qq*8+6][r] = a1.z; As[qq*8+7][r] = a1.w;
    Bs[qq*8+0][r] = b0.x; Bs[qq*8+1][r] = b0.y; Bs[qq*8+2][r] = b0.z; Bs[qq*8+3][r] = b0.w;
    Bs[qq*8+4][r] = b1.x; Bs[qq*8+5][r] = b1.y; Bs[qq*8+6][r] = b1.z; Bs[qq*8+7][r] = b1.w;
    __syncthreads();
#pragma unroll
    for (int kk = 0; kk < 16; ++kk) {
      float4 av0 = *(const float4*)&As[kk][ty*8];
      float4 av1 = *(const float4*)&As[kk][ty*8+4];
      float4 bv0 = *(const float4*)&Bs[kk][tx*8];
      float4 bv1 = *(const float4*)&Bs[kk][tx*8+4];
      float am[8] = {av0.x,av0.y,av0.z,av0.w,av1.x,av1.y,av1.z,av1.w};
      float bn[8] = {bv0.x,bv0.y,bv0.z,bv0.w,bv1.x,bv1.y,bv1.z,bv1.w};
#pragma unroll
      for (int i = 0; i < 8; ++i)
#pragma unroll
        for (int j = 0; j < 8; ++j)
          acc[i][j] = fmaf(am[i], bn[j], acc[i][j]);
    }
  }
  const float* bi_p = dir ? bihb : bihf;
  const float* bh_p = dir ? bhhb : bhhf;
  float bias[8];
#pragma unroll
  for (int j = 0; j < 8; ++j) { int n = n0 + tx*8 + j; bias[j] = bi_p[n] + bh_p[n]; }
  const int mb = m0 + ty * 8;
  const int tt = mb >> 5, bb = mb & 31;
#pragma unroll
  for (int j = 0; j < 8; ++j) {
    int n = n0 + tx*8 + j;
    float* dst = &xproj[((((size_t)dir*512 + tt)*1024) + n)*32 + bb];
    float4 s0 = make_float4(acc[0][j]+bias[j], acc[1][j]+bias[j], acc[2][j]+bias[j], acc[3][j]+bias[j]);
    float4 s1 = make_float4(acc[4][j]+bias[j], acc[5][j]+bias[j], acc[6][j]+bias[j], acc[7][j]+bias[j]);
    *(float4*)dst = s0;
    *(float4*)(dst + 4) = s1;
  }
}

// ---------------- K3: persistent bidirectional LSTM ----------------
// 64 WGs: dir = wg>>5, slice = wg&31 (8 j's). Sentinel protocol: hist slot s holds
// the h INPUT of step s (slot 0 unused; step 0 reads h0 directly). Producers write
// slot s+1 right after the cell update with fire-and-forget dwordx4 sc0sc1 stores
// (data IS the flag). Consumers use a TWO-PHASE poll: phase 1 spins on chunk 7
// only (1 KB/wave/iter instead of 8 KB -- avoids self-congesting the MALL path);
// phase 2 bulk-loads chunks 0..6 and verifies (typically 1 iter). Barriers are
// lgkm-only; the next poll's vmcnt(0) retires the publish stores (WAR-safe).
// hist slot layout: [bh=b>>2][j][bl=b&3]  (8*256*4 floats = 32 KB)
__global__ __launch_bounds__(256, 1) void k_lstm(
    const float* __restrict__ whhf, const float* __restrict__ whhb,
    const float* __restrict__ h0, const float* __restrict__ c0,
    const float* __restrict__ xproj, float* __restrict__ hist)
{
  const int wg = blockIdx.x;           // 0..63
  const int dir = wg >> 5;
  const int slice = wg & 31;
  const int tid = threadIdx.x;
  const int rowg = tid >> 5;           // 0..7 => j_local
  const int bgrp = (tid >> 3) & 3;     // 0..3
  const int kgrp = tid & 7;            // 0..7
  const int jg = slice * 8 + rowg;     // 0..255
  const float* __restrict__ W = dir ? whhb : whhf;
  __shared__ float hl[32 * 256];

  // weights -> registers: w2[gate][kk2] covers k = kgrp*32 + 2*kk2 (+1)
  float2 w2[4][16];
#pragma unroll
  for (int g = 0; g < 4; ++g)
#pragma unroll
    for (int kk2 = 0; kk2 < 16; ++kk2)
      w2[g][kk2] = *(const float2*)&W[(size_t)(g*256 + jg)*256 + kgrp*32 + 2*kk2];

  // cell state (redundant across kgrp lanes)
  float cc[8];
#pragma unroll
  for (int bi = 0; bi < 8; ++bi)
    cc[bi] = c0[(size_t)(dir*32 + bgrp*8 + bi)*256 + jg];

  const int kk = tid & 31;
  const int base_col = tid & ~31;
  const int kw4 = 4*((tid >> 5) & 7);
  const int rot = (4*kgrp + 2*bgrp) & 31;
  float* const histd = hist + (size_t)dir * 513 * 8192;
  float hnew[8];

  for (int s = 0; s < 512; ++s) {
    const int t = dir ? (511 - s) : s;

    // (a) obtain h input: column j = tid, all 32 b
    vf4 hv[8];
    if (s == 0) {
#pragma unroll
      for (int q = 0; q < 8; ++q)
#pragma unroll
        for (int bl = 0; bl < 4; ++bl)
          hv[q][bl] = h0[(size_t)(dir*32 + 4*q + bl)*256 + tid];
    } else {
      const float* sp = histd + (size_t)s*8192 + (size_t)tid*4;
      const float* p0 = sp;
      const float* p1 = sp + 1024;
      const float* p2 = sp + 2048;
      const float* p3 = sp + 3072;
      const float* p4 = sp + 4096;
      const float* p5 = sp + 5120;
      const float* p6 = sp + 6144;
      const float* p7 = sp + 7168;
      // phase 1: spin on chunk 7 only (small footprint, low VALU)
      while (true) {
        asm volatile(
          "global_load_dwordx4 %0, %1, off sc0 sc1\n\t"
          "s_waitcnt vmcnt(0)"
          : "=v"(hv[7]) : "v"(p7) : "memory");
        unsigned z = 0xFFFFFFFFu;
#pragma unroll
        for (int bl = 0; bl < 4; ++bl)
          z = um(z, __float_as_uint(hv[7][bl]) ^ SENTU);
        if (z) break;
        __builtin_amdgcn_s_sleep(1);
      }
      // phase 2: bulk load chunks 0..6, verify all 28 words (usually 1 iter)
      while (true) {
        asm volatile(
          "global_load_dwordx4 %0, %7, off sc0 sc1\n\t"
          "global_load_dwordx4 %1, %8, off sc0 sc1\n\t"
          "global_load_dwordx4 %2, %9, off sc0 sc1\n\t"
          "global_load_dwordx4 %3, %10, off sc0 sc1\n\t"
          "global_load_dwordx4 %4, %11, off sc0 sc1\n\t"
          "global_load_dwordx4 %5, %12, off sc0 sc1\n\t"
          "global_load_dwordx4 %6, %13, off sc0 sc1\n\t"
          "s_waitcnt vmcnt(0)"
          : "=&v"(hv[0]), "=&v"(hv[1]), "=&v"(hv[2]), "=&v"(hv[3]),
            "=&v"(hv[4]), "=&v"(hv[5]), "=&v"(hv[6])
          : "v"(p0), "v"(p1), "v"(p2), "v"(p3),
            "v"(p4), "v"(p5), "v"(p6)
          : "memory");
        unsigned z = 0xFFFFFFFFu;
#pragma unroll
        for (int q = 0; q < 7; ++q)
#pragma unroll
          for (int bl = 0; bl < 4; ++bl)
            z = um(z, __float_as_uint(hv[q][bl]) ^ SENTU);
        if (z) break;
        __builtin_amdgcn_s_sleep(1);
      }
    }

    // (b) xproj prefetch for THIS step, issued AFTER the poll so the poll's
    // vmcnt(0) never drains it; consumed after the FMA block (~1.2us cover).
    float xpr[4][8];
    if (kgrp == 0) {
#pragma unroll
      for (int g = 0; g < 4; ++g) {
        const float* xp = &xproj[((((size_t)dir*512 + t)*1024) + g*256 + jg)*32 + bgrp*8];
        float4 x0 = *(const float4*)xp;
        float4 x1 = *(const float4*)(xp + 4);
        xpr[g][0]=x0.x; xpr[g][1]=x0.y; xpr[g][2]=x0.z; xpr[g][3]=x0.w;
        xpr[g][4]=x1.x; xpr[g][5]=x1.y; xpr[g][6]=x1.z; xpr[g][7]=x1.w;
      }
    }

    // (c) scatter to LDS with rotation swizzle (identical hl contents as verified)
#pragma unroll
    for (int q = 0; q < 8; ++q) {
      const int rwq = (kw4 + 2*((q >> 1) & 3)) & 31;
      const int col = base_col + ((kk + rwq) & 31);
#pragma unroll
      for (int bl = 0; bl < 4; ++bl)
        hl[(4*q + bl)*256 + col] = hv[q][bl];
    }
    BARRIER_LGKM();

    // (d) gates partial sums over our 32-k slice
    float acc[4][8];
#pragma unroll
    for (int g = 0; g < 4; ++g)
#pragma unroll
      for (int bi = 0; bi < 8; ++bi) acc[g][bi] = 0.f;

    const int hbase = kgrp * 32;
#pragma unroll
    for (int kk2 = 0; kk2 < 16; ++kk2) {
      const int idx = hbase + ((2*kk2 + rot) & 31);
      float2 h2[8];
#pragma unroll
      for (int bi = 0; bi < 8; ++bi)
        h2[bi] = *(const float2*)&hl[(bgrp*8 + bi)*256 + idx];
#pragma unroll
      for (int g = 0; g < 4; ++g)
#pragma unroll
        for (int bi = 0; bi < 8; ++bi) {
          acc[g][bi] = fmaf(w2[g][kk2].x, h2[bi].x, acc[g][bi]);
          acc[g][bi] = fmaf(w2[g][kk2].y, h2[bi].y, acc[g][bi]);
        }
    }

    // (e) xproj term once (kgrp==0), then butterfly-reduce over the 8 kgrp lanes
    if (kgrp == 0) {
#pragma unroll
      for (int g = 0; g < 4; ++g)
#pragma unroll
        for (int bi = 0; bi < 8; ++bi) acc[g][bi] += xpr[g][bi];
    }
#pragma unroll
    for (int g = 0; g < 4; ++g)
#pragma unroll
      for (int bi = 0; bi < 8; ++bi) {
        float v = acc[g][bi];
        v += __shfl_xor(v, 1, 64);
        v += __shfl_xor(v, 2, 64);
        v += __shfl_xor(v, 4, 64);
        acc[g][bi] = v;
      }

    // (f) LSTM cell update (PyTorch gate order i,f,g,o)
#pragma unroll
    for (int bi = 0; bi < 8; ++bi) {
      float ig = fsig(acc[0][bi]);
      float fg = fsig(acc[1][bi]);
      float gg = ftanh(acc[2][bi]);
      float og = fsig(acc[3][bi]);
      cc[bi] = fg * cc[bi] + ig * gg;
      hnew[bi] = og * ftanh(cc[bi]);
    }

    // (g) publish h into slot s+1 immediately (fire & forget; rides across the
    // barrier below; next poll's vmcnt(0) retires it before hnew is rewritten)
    if (kgrp == 0) {
      float* dp  = histd + (size_t)(s + 1)*8192 + ((size_t)(2*bgrp)*256 + jg)*4;
      float* dp2 = dp + 1024;
      vf4 s0; s0.x = hnew[0]; s0.y = hnew[1]; s0.z = hnew[2]; s0.w = hnew[3];
      vf4 s1; s1.x = hnew[4]; s1.y = hnew[5]; s1.z = hnew[6]; s1.w = hnew[7];
      asm volatile(
        "global_store_dwordx4 %0, %2, off sc0 sc1\n\t"
        "global_store_dwordx4 %1, %3, off sc0 sc1"
        :: "v"(dp), "v"(dp2), "v"(s0), "v"(s1) : "memory");
    }

    BARRIER_LGKM();   // protect hl before next scatter (no vmcnt drain)
  }
}

// ---------------- K4: feats = hs @ w_out^T + b_out (reads hist) ----------------
// fwd h-output at time t = hist[0][t+1]; bwd h-output at time t = hist[1][512-t]
__global__ __launch_bounds__(256) void k_feats(
    const float* __restrict__ hist, const float* __restrict__ wout,
    const float* __restrict__ bout, float* __restrict__ feats)
{
  const int t = blockIdx.x;
  const int tid = threadIdx.x;
  __shared__ float hlds[32 * 516];
#pragma unroll
  for (int dir = 0; dir < 2; ++dir) {
    const int slot = dir ? (512 - t) : (t + 1);
    const float* sp = hist + ((size_t)dir*513 + slot)*8192;
#pragma unroll
    for (int q = 0; q < 8; ++q) {
      vf4 v = *(const vf4*)&sp[(size_t)(q*256 + tid)*4];
      float* d = &hlds[(4*q)*516 + dir*256 + tid];
      d[0*516] = v.x; d[1*516] = v.y; d[2*516] = v.z; d[3*516] = v.w;
    }
  }
  __syncthreads();
  const int b = tid >> 3, ks = tid & 7;
#pragma unroll
  for (int kt = 0; kt < 3; ++kt) {
    int k = kt * 8 + ks;
    float acc = bout[k];
    const float* wr = wout + (size_t)k * 512;
#pragma unroll 8
    for (int kk = 0; kk < 512; kk += 4) {
      float4 h4 = *(const float4*)&hlds[b * 516 + kk];
      float4 w4 = *(const float4*)&wr[kk];
      acc += h4.x*w4.x + h4.y*w4.y + h4.z*w4.z + h4.w*w4.w;
    }
    feats[((size_t)t * 32 + b) * 24 + k] = acc;
  }
}

// ---------------- K5: Viterbi + backtrace, one wave per batch element ----------------
__global__ __launch_bounds__(64) void k_viterbi(
    const float* __restrict__ feats, const float* __restrict__ trans,
    float* __restrict__ out)
{
  const int b = blockIdx.x;      // 0..31
  const int lane = threadIdx.x;  // 0..63 ; active tag lane if <24
  const int k = lane;
  __shared__ float fvl[2][32];
  __shared__ float pathb[512];
  __shared__ unsigned char bcol[512 * 24];
  float trr[24];
  if (k < 24) {
#pragma unroll
    for (int pv = 0; pv < 24; ++pv) trr[pv] = trans[k * 24 + pv];
  }
  if (k < 32) fvl[0][k] = (k == START_TAG) ? 0.f : NEGV;
  if (k < 32) fvl[1][k] = NEGV;
  __syncthreads();
  float fcur = (k < 24) ? feats[b * 24 + k] : 0.f;
  int q = 0;
  for (int t = 0; t < 512; ++t) {
    float fnext = (t < 511 && k < 24) ? feats[(size_t)(t + 1) * 768 + b * 24 + k] : 0.f;
    float fvp[24];
    {
      const float4* fp4 = (const float4*)&fvl[q][0];
#pragma unroll
      for (int i = 0; i < 6; ++i) {
        float4 v = fp4[i];
        fvp[i*4+0] = v.x; fvp[i*4+1] = v.y; fvp[i*4+2] = v.z; fvp[i*4+3] = v.w;
      }
    }
    float best = -3.4e38f; int bp = 0;
#pragma unroll
    for (int pv = 0; pv < 24; ++pv) {
      float v = fvp[pv] + trr[pv];
      if (v > best) { best = v; bp = pv; }   // strict > : first-max, matches argmax
    }
    if (k < 24) {
      fvl[q ^ 1][k] = best + fcur;
      bcol[t * 24 + k] = (unsigned char)bp;
    }
    fcur = fnext;
    q ^= 1;
    __syncthreads();
  }
  if (lane == 0) {
    float best = -3.4e38f; int bt = 0;
#pragma unroll
    for (int kk = 0; kk < 24; ++kk) {
      float v = fvl[q][kk] + trans[STOP_TAG * 24 + kk];
      if (v > best) { best = v; bt = kk; }
    }
    out[b] = best;
    pathb[511] = (float)bt;
    int tag = bt;
    for (int t = 511; t >= 1; --t) {
      tag = bcol[t * 24 + tag];
      pathb[t - 1] = (float)tag;
    }
  }
  __syncthreads();
#pragma unroll
  for (int it = 0; it < 8; ++it)
    out[32 + (size_t)b * 512 + it * 64 + lane] = pathb[it * 64 + lane];
}

// ---------------- launch ----------------
extern "C" void kernel_launch(void* const* d_in, const int* in_sizes, int n_in,
                              void* d_out, int out_size, void* d_ws, size_t ws_size,
                              hipStream_t stream) {
  (void)in_sizes; (void)n_in; (void)out_size; (void)ws_size;
  const int*   sent = (const int*)d_in[0];
  const float* emb  = (const float*)d_in[1];
  const float* wihf = (const float*)d_in[2];
  const float* whhf = (const float*)d_in[3];
  const float* bihf = (const float*)d_in[4];
  const float* bhhf = (const float*)d_in[5];
  const float* wihb = (const float*)d_in[6];
  const float* whhb = (const float*)d_in[7];
  const float* bihb = (const float*)d_in[8];
  const float* bhhb = (const float*)d_in[9];
  const float* wout = (const float*)d_in[10];
  const float* bout = (const float*)d_in[11];
  const float* trans= (const float*)d_in[12];
  const float* h0   = (const float*)d_in[13];
  const float* c0   = (const float*)d_in[14];

  float* ws     = (float*)d_ws;
  float* xproj  = ws + XPROJ_OFF;
  float* feats  = ws + FEATS_OFF;
  float* hist   = ws + HIST_OFF;

  const int n4 = (int)(HIST_ELEMS / 4);   // 2,101,248 dwordx4 stores, exact cover
  k_fill<<<(n4 + 255) / 256, 256, 0, stream>>>(hist, n4);
  k_xproj<<<dim3(128, 8, 2), 256, 0, stream>>>(sent, emb, wihf, wihb,
                                               bihf, bhhf, bihb, bhhb, xproj);
  k_lstm<<<64, 256, 0, stream>>>(whhf, whhb, h0, c0, xproj, hist);
  k_feats<<<512, 256, 0, stream>>>(hist, wout, bout, feats);
  k_viterbi<<<32, 64, 0, stream>>>(feats, trans, (float*)d_out);
}